// Round 1
// baseline (1680.347 us; speedup 1.0000x reference)
//
#include <hip/hip_runtime.h>
#include <cmath>

#define B_   32
#define S_   128
#define E_   300
#define C_   100
#define EC_  50
#define LC_  50
#define H_   256
#define G4_  1024   // 4*H
#define L_   17
#define DHID_ 400   // E + C
#define NBLKD 8     // lstm blocks per direction
#define SLAB_ 8192  // u32 per (d,t) frag slab: [Nt(2)][Kt(8)][lane(64)][hi m0..3 | lo m4..7]
#define SENT2_ 0x7E007E00u  // fp16-NaN in both halves: legit packed pair never matches
#define SENTF_ 0x7FC0DEADu  // fp32 qNaN sentinel: legit finite result never matches
#define KP_   208   // k-pairs per row in packed GEMM operands (416 k, zero-padded from 400)

// ---- mega-kernel role layout (dispatch order = dependency-safe order) ----
#define RB_LSTM 0
#define NB_LSTM 16
#define RB_C1   16
#define NB_C1   64
#define RB_C2   80
#define NB_C2   128
#define RB_C3   208
#define NB_C3   160
#define RB_PW   368
#define NB_PW   64
#define RB_PB   432
#define NB_PB   512
#define RB_GEMM 944
#define NB_GEMM 512
#define RB_FC   1456
#define NB_FC   128
#define RB_SMV  1584
#define NB_SMV  32
#define NBLK_MEGA 1616

#define F_C1 0
#define F_C2 1
#define F_C3 2
#define F_PW 3
#define F_PB 4

typedef _Float16 half8 __attribute__((ext_vector_type(8)));
typedef float f32x4 __attribute__((ext_vector_type(4)));
typedef unsigned long long ull;
struct __align__(16) U2 { ull x, y; };

// split fp32 -> (hi fp16, lo fp16 scaled by 2048), packed u32 (hi in low16).
__device__ __forceinline__ unsigned pack_split(float v) {
  _Float16 hi = (fabsf(v) >= 6.104e-5f) ? (_Float16)v : (_Float16)0.0f;
  float hif = (float)hi;
  _Float16 lo = (_Float16)((v - hif) * 2048.0f);
  return (unsigned)__builtin_bit_cast(unsigned short, hi)
       | ((unsigned)__builtin_bit_cast(unsigned short, lo) << 16);
}

__device__ __forceinline__ void flag_signal(int* f) {
  __syncthreads();   // all threads' plain stores drained (waitcnt before s_barrier)
  if (threadIdx.x == 0)
    __hip_atomic_fetch_add(f, 1, __ATOMIC_RELEASE, __HIP_MEMORY_SCOPE_AGENT);
}
__device__ __forceinline__ void flag_wait(const int* f, int target, int slp) {
  while (__hip_atomic_load(f, __ATOMIC_ACQUIRE, __HIP_MEMORY_SCOPE_AGENT) < target) {
    switch (slp) {
      case 4:  __builtin_amdgcn_s_sleep(4);  break;
      case 8:  __builtin_amdgcn_s_sleep(8);  break;
      default: __builtin_amdgcn_s_sleep(16); break;
    }
  }
}

// LDS union: one static allocation, role-dependent view. Max member = conv3 (61.5 KB).
union SMem {
  struct { unsigned aH[2048], aL[2048], bH[2048], bL[2048]; } gemm;                     // 32 KB
  struct { ull slh[2048], sll[2048]; float gl[4 * 32 * 33]; unsigned ps[2 * 576]; } lstm; // 54.2 KB
  struct { float ce[EC_ * 52]; float wl[50 * 150]; int ids[LC_]; } c1;
  struct { float il[C_ * 48]; float wl[25 * 400]; } c2;                                  // 59.2 KB
  struct { float il[C_ * 45]; float wl[20 * 500]; float o3[20 * 44]; } c3;               // 61.5 KB
  struct { float wT[512 * 18]; float psum[256 * 18]; } fc;                               // 55.3 KB
  struct { float e[S_ * L_]; float tr[L_ * L_]; float sc[2][L_];
           int hist[(S_ - 1) * L_]; int tags[S_]; } smv;
};

// ---------------------------------------------------------------- fill: hfrag init + sentinels + flags
__global__ void k_fill(const float* __restrict__ h0, unsigned* __restrict__ hfrag,
                       unsigned* __restrict__ hbufU, unsigned* __restrict__ giU,
                       unsigned* __restrict__ emU, int* __restrict__ flags) {
  const int g0 = blockIdx.x * 256 + threadIdx.x;
  const int nth = gridDim.x * 256;
  // hfrag: t=0 packed from h0, t>=1 sentinel (identical to previous k_hinit)
  const int htot = 2 * (S_ + 1) * SLAB_;
  for (int idx = g0; idx < htot; idx += nth) {
    int sd = idx / SLAB_;
    int within = idx % SLAB_;
    int t = sd % (S_ + 1), d = sd / (S_ + 1);
    if (t != 0) { hfrag[idx] = SENT2_; continue; }
    int m8 = within & 7;
    int lane = (within >> 3) & 63;
    int q = within >> 9;
    int Kt = q & 7, Nt = q >> 3;
    int m = m8 & 3, isLo = m8 >> 2;
    int k0 = Kt * 32 + (lane >> 4) * 8 + 2 * m;
    int b = Nt * 16 + (lane & 15);
    unsigned p0 = pack_split(h0[((size_t)d * B_ + b) * H_ + k0]);
    unsigned p1 = pack_split(h0[((size_t)d * B_ + b) * H_ + k0 + 1]);
    unsigned hiw = (p0 & 0xFFFFu) | (p1 << 16);
    unsigned low = (p0 >> 16) | (p1 & 0xFFFF0000u);
    hfrag[idx] = isLo ? low : hiw;
  }
  const int hbtot = 2 * (S_ + 1) * H_ * B_;
  for (int idx = g0; idx < hbtot; idx += nth) hbufU[idx] = SENTF_;
  const int gtot = 2 * S_ * G4_ * B_;
  for (int idx = g0; idx < gtot; idx += nth) giU[idx] = SENTF_;
  const int etot = B_ * S_ * L_;
  for (int idx = g0; idx < etot; idx += nth) emU[idx] = SENTF_;
  if (g0 < 16) flags[g0] = 0;
}

// ---------------------------------------------------------------- mega: all stages, one launch
__global__ __launch_bounds__(256, 2) void k_mega(
    const int* __restrict__ x, const int* __restrict__ x_char,
    const float* __restrict__ word_emb, const float* __restrict__ char_emb,
    const float* __restrict__ conv1_w, const float* __restrict__ conv1_b,
    const float* __restrict__ conv2_w, const float* __restrict__ conv2_b,
    const float* __restrict__ conv3_w, const float* __restrict__ conv3_b,
    const float* __restrict__ w_ih_f, const float* __restrict__ w_ih_b,
    const float* __restrict__ w_hh_f, const float* __restrict__ w_hh_b,
    const float* __restrict__ b_f, const float* __restrict__ b_b,
    const float* __restrict__ c0,
    const float* __restrict__ fc_w, const float* __restrict__ fc_b,
    const float* __restrict__ start_t, const float* __restrict__ trans,
    const float* __restrict__ end_t,
    float* __restrict__ pooled, float* __restrict__ gi, float* __restrict__ hbuf,
    unsigned* __restrict__ hfrag,
    unsigned* __restrict__ apH, unsigned* __restrict__ apL,
    unsigned* __restrict__ bpH, unsigned* __restrict__ bpL,
    float* __restrict__ out1, float* __restrict__ out2,
    float* __restrict__ em, int* __restrict__ flags, int* __restrict__ out) {
  const int bid = blockIdx.x;
  __shared__ SMem sm;

  // ================================================================ LSTM (bids 0..15)
  if (bid < RB_C1) {
    __builtin_amdgcn_s_setprio(2);  // recurrence is the critical path; win CU arbitration
    const int iblk = bid & 7;
    const int d = bid >> 3;
    const float* whh = d ? w_hh_b : w_hh_f;
    const int tid = threadIdx.x;
    const int w = tid >> 6;          // wave index = gate (i,f,g,o)
    const int l = tid & 63;
    const int lx = l & 15, lq = l >> 4;
    const int u0 = iblk * 32;

    ull* slh = sm.lstm.slh;
    ull* sll = sm.lstm.sll;
    float* glb = sm.lstm.gl;
    unsigned* ps = sm.lstm.ps;

    half8 whi[2][8], wlo[2][8];
#pragma unroll
    for (int Mt = 0; Mt < 2; ++Mt) {
#pragma unroll
      for (int Kt = 0; Kt < 8; ++Kt) {
        int row = w * H_ + u0 + Mt * 16 + lx;
        int kk0 = Kt * 32 + lq * 8;
        const float* src = whh + (size_t)row * H_ + kk0;
        float4 f0 = *(const float4*)src;
        float4 f1 = *(const float4*)(src + 4);
        float wv[8] = {f0.x, f0.y, f0.z, f0.w, f1.x, f1.y, f1.z, f1.w};
        union { unsigned short s2[8]; half8 h; } HI, LO;
#pragma unroll
        for (int j = 0; j < 8; ++j) {
          float v = wv[j];
          _Float16 hi = (fabsf(v) >= 6.104e-5f) ? (_Float16)v : (_Float16)0.0f;
          float hif = (float)hi;
          _Float16 lo = (_Float16)((v - hif) * 2048.0f);
          HI.s2[j] = __builtin_bit_cast(unsigned short, hi);
          LO.s2[j] = __builtin_bit_cast(unsigned short, lo);
        }
        whi[Mt][Kt] = HI.h;
        wlo[Mt][Kt] = LO.h;
      }
    }

    const int bc = tid & 31, cw = tid >> 5;
    float creg[4];
#pragma unroll
    for (int cu = 0; cu < 4; ++cu)
      creg[cu] = c0[((size_t)d * B_ + bc) * H_ + u0 + cu * 8 + cw];

    const int pNt = bc >> 4;
    const int pm = cw >> 1;
    const bool phi = (cw & 1) == 0;
    const int plane = bc & 15;
    const float inv2048 = 1.0f / 2048.0f;

    for (int t = 0; t < S_; ++t) {
      int torig = d ? (S_ - 1 - t) : t;

      // gi loads issued first (sentinel-gated; ready in steady state — check deferred
      // until after the hfrag spin so their latency hides under it)
      const unsigned* gbase = (const unsigned*)gi + ((size_t)(d * S_ + torig) * G4_) * B_;
      unsigned gv[2][2][4];
#pragma unroll
      for (int Mt = 0; Mt < 2; ++Mt)
#pragma unroll
        for (int Nt = 0; Nt < 2; ++Nt)
#pragma unroll
          for (int r = 0; r < 4; ++r) {
            int j = w * H_ + u0 + Mt * 16 + lq * 4 + r;
            gv[Mt][Nt][r] = __hip_atomic_load(&gbase[(size_t)j * B_ + Nt * 16 + lx],
                                              __ATOMIC_RELAXED, __HIP_MEMORY_SCOPE_AGENT);
          }

      // spin on previous-step h fragments (unchanged protocol)
      const ull* hp = (const ull*)(hfrag + (size_t)(d * (S_ + 1) + t) * SLAB_);
      ull pv[4][4];
#pragma unroll
      for (int c = 0; c < 4; ++c) {
        size_t base = ((size_t)(w * 4 + c) * 64 + l) * 4;
#pragma unroll
        for (int j = 0; j < 4; ++j)
          pv[c][j] = __hip_atomic_load(&hp[base + j], __ATOMIC_RELAXED,
                                       __HIP_MEMORY_SCOPE_AGENT);
      }
      for (;;) {
        bool pending = false;
#pragma unroll
        for (int c = 0; c < 4; ++c)
#pragma unroll
          for (int j = 0; j < 4; ++j)
            pending |= ((unsigned)pv[c][j] == SENT2_) |
                       ((unsigned)(pv[c][j] >> 32) == SENT2_);
        if (!pending) break;
#pragma unroll
        for (int c = 0; c < 4; ++c) {
          size_t base = ((size_t)(w * 4 + c) * 64 + l) * 4;
#pragma unroll
          for (int j = 0; j < 4; ++j)
            pv[c][j] = __hip_atomic_load(&hp[base + j], __ATOMIC_RELAXED,
                                         __HIP_MEMORY_SCOPE_AGENT);
        }
      }

      // gi sentinel check (rare retries — only while gemm is still ahead of us)
      for (;;) {
        bool pending = false;
#pragma unroll
        for (int Mt = 0; Mt < 2; ++Mt)
#pragma unroll
          for (int Nt = 0; Nt < 2; ++Nt)
#pragma unroll
            for (int r = 0; r < 4; ++r) pending |= (gv[Mt][Nt][r] == SENTF_);
        if (!pending) break;
#pragma unroll
        for (int Mt = 0; Mt < 2; ++Mt)
#pragma unroll
          for (int Nt = 0; Nt < 2; ++Nt)
#pragma unroll
            for (int r = 0; r < 4; ++r) {
              int j = w * H_ + u0 + Mt * 16 + lq * 4 + r;
              gv[Mt][Nt][r] = __hip_atomic_load(&gbase[(size_t)j * B_ + Nt * 16 + lx],
                                                __ATOMIC_RELAXED, __HIP_MEMORY_SCOPE_AGENT);
            }
      }

      f32x4 acch[2][2], accl[2][2];
#pragma unroll
      for (int Mt = 0; Mt < 2; ++Mt)
#pragma unroll
        for (int Nt = 0; Nt < 2; ++Nt) {
          f32x4 v, z = {0.f, 0.f, 0.f, 0.f};
#pragma unroll
          for (int r = 0; r < 4; ++r) v[r] = __builtin_bit_cast(float, gv[Mt][Nt][r]);
          acch[Mt][Nt] = v;
          accl[Mt][Nt] = z;
        }

#pragma unroll
      for (int c = 0; c < 4; ++c) {
        int idx = ((w * 4 + c) * 64 + l) * 2;
        U2 vh; vh.x = pv[c][0]; vh.y = pv[c][1];
        U2 vl; vl.x = pv[c][2]; vl.y = pv[c][3];
        *(U2*)&slh[idx] = vh;
        *(U2*)&sll[idx] = vl;
      }
      __syncthreads();

#pragma unroll
      for (int Kt = 0; Kt < 8; ++Kt) {
        half8 Bhi[2], Blo[2];
#pragma unroll
        for (int Nt = 0; Nt < 2; ++Nt) {
          int idx = ((Nt * 8 + Kt) * 64 + l) * 2;
          union { U2 u; half8 h; } UH, UL;
          UH.u = *(const U2*)&slh[idx];
          UL.u = *(const U2*)&sll[idx];
          Bhi[Nt] = UH.h;
          Blo[Nt] = UL.h;
        }
#pragma unroll
        for (int Mt = 0; Mt < 2; ++Mt)
#pragma unroll
          for (int Nt = 0; Nt < 2; ++Nt) {
            acch[Mt][Nt] = __builtin_amdgcn_mfma_f32_16x16x32_f16(
                whi[Mt][Kt], Bhi[Nt], acch[Mt][Nt], 0, 0, 0);
            accl[Mt][Nt] = __builtin_amdgcn_mfma_f32_16x16x32_f16(
                whi[Mt][Kt], Blo[Nt], accl[Mt][Nt], 0, 0, 0);
            accl[Mt][Nt] = __builtin_amdgcn_mfma_f32_16x16x32_f16(
                wlo[Mt][Kt], Bhi[Nt], accl[Mt][Nt], 0, 0, 0);
          }
      }

#pragma unroll
      for (int Mt = 0; Mt < 2; ++Mt)
#pragma unroll
        for (int Nt = 0; Nt < 2; ++Nt)
#pragma unroll
          for (int r = 0; r < 4; ++r) {
            int ul = Mt * 16 + lq * 4 + r;
            glb[(w * 32 + ul) * 33 + Nt * 16 + lx] =
                acch[Mt][Nt][r] + accl[Mt][Nt][r] * inv2048;
          }
      __syncthreads();

      float hreg[4];
#pragma unroll
      for (int cu = 0; cu < 4; ++cu) {
        int u = cu * 8 + cw;
        float g_i = glb[(0 * 32 + u) * 33 + bc];
        float g_f = glb[(1 * 32 + u) * 33 + bc];
        float g_g = glb[(2 * 32 + u) * 33 + bc];
        float g_o = glb[(3 * 32 + u) * 33 + bc];
        float si = 1.f / (1.f + __expf(-g_i));
        float sf = 1.f / (1.f + __expf(-g_f));
        float so = 1.f / (1.f + __expf(-g_o));
        float tg = 1.f - 2.f / (__expf(2.f * g_g) + 1.f);
        float cn = sf * creg[cu] + si * tg;
        float tc = 1.f - 2.f / (__expf(2.f * cn) + 1.f);
        float hn = so * tc;
        creg[cu] = cn;
        hreg[cu] = hn;
        unsigned me = pack_split(hn);
        unsigned pa = (unsigned)__shfl_xor((int)me, 32, 64);
        unsigned je = (cw & 1) ? pa : me;
        unsigned jo = (cw & 1) ? me : pa;
        unsigned hiw = (je & 0xFFFFu) | (jo << 16);
        unsigned low = (je >> 16) | (jo & 0xFFFF0000u);
        int lane2 = (cu << 4) | plane;
        int m8 = phi ? pm : (4 + pm);
        ps[pNt * 576 + lane2 * 9 + m8] = phi ? hiw : low;
      }
      __syncthreads();

      {
        ull* slab64 = (ull*)(hfrag + (size_t)(d * (S_ + 1) + t + 1) * SLAB_);
#pragma unroll
        for (int hh2 = 0; hh2 < 2; ++hh2) {
          int r = tid;
          int Nt = hh2;
          int lane2 = r >> 2, m2 = r & 3;
          unsigned a = ps[Nt * 576 + lane2 * 9 + 2 * m2];
          unsigned b2 = ps[Nt * 576 + lane2 * 9 + 2 * m2 + 1];
          ull v = (ull)a | ((ull)b2 << 32);
          __hip_atomic_store(&slab64[(size_t)(Nt * 8 + iblk) * 256 + r], v,
                             __ATOMIC_RELAXED, __HIP_MEMORY_SCOPE_AGENT);
        }
        // hbuf now published with device-visible relaxed stores (fc polls it)
        float* hb = hbuf + (size_t)(d * (S_ + 1) + t + 1) * (H_ * B_) + u0 * B_;
#pragma unroll
        for (int cu = 0; cu < 4; ++cu)
          __hip_atomic_store(&hb[cu * 256 + tid], hreg[cu],
                             __ATOMIC_RELAXED, __HIP_MEMORY_SCOPE_AGENT);
      }
    }
    return;
  }

  // ================================================================ conv1 (64 blocks)
  else if (bid < RB_C2) {
    const int q = bid - RB_C1;
    const int b2 = q & 31, ot = q >> 5;
    float* ce = sm.c1.ce;
    float* wl = sm.c1.wl;
    int* ids = sm.c1.ids;
    const int tid = threadIdx.x;
    if (tid < LC_) ids[tid] = x_char[b2 * LC_ + tid];
    __syncthreads();
    for (int idx = tid; idx < LC_ * EC_; idx += 256) {
      int t2 = idx / EC_, ec = idx % EC_;
      ce[ec * 52 + t2] = char_emb[ids[t2] * EC_ + ec];
    }
    int obase = ot * 50;
    for (int idx = tid; idx < 50 * 150; idx += 256)
      wl[idx] = conv1_w[obase * 150 + idx];
    __syncthreads();
    for (int idx = tid; idx < 50 * 48; idx += 256) {
      int o = idx / 48, t2 = idx % 48;
      float acc = conv1_b[obase + o];
      const float* wr = &wl[o * 150];
      for (int c = 0; c < EC_; ++c) {
        const float* ip = &ce[c * 52 + t2];
        acc += wr[c * 3 + 0] * ip[0] + wr[c * 3 + 1] * ip[1] + wr[c * 3 + 2] * ip[2];
      }
      out1[((size_t)b2 * C_ + obase + o) * 48 + t2] = fmaxf(acc, 0.0f);
    }
    flag_signal(&flags[F_C1]);
    return;
  }

  // ================================================================ conv2 (128 blocks)
  else if (bid < RB_C3) {
    flag_wait(&flags[F_C1], NB_C1, 4);
    const int q = bid - RB_C2;
    const int b2 = q & 31, ot = q >> 5;
    float* il = sm.c2.il;
    float* wl = sm.c2.wl;
    const int tid = threadIdx.x;
    for (int idx = tid; idx < C_ * 48; idx += 256) il[idx] = out1[(size_t)b2 * C_ * 48 + idx];
    int obase = ot * 25;
    for (int idx = tid; idx < 25 * 400; idx += 256) wl[idx] = conv2_w[obase * 400 + idx];
    __syncthreads();
    for (int idx = tid; idx < 25 * 45; idx += 256) {
      int o = idx / 45, t2 = idx % 45;
      float acc = conv2_b[obase + o];
      const float* wr = &wl[o * 400];
      for (int c = 0; c < C_; ++c) {
        const float* ip = &il[c * 48 + t2];
        acc += wr[c * 4 + 0] * ip[0] + wr[c * 4 + 1] * ip[1] +
               wr[c * 4 + 2] * ip[2] + wr[c * 4 + 3] * ip[3];
      }
      out2[((size_t)b2 * C_ + obase + o) * 45 + t2] = fmaxf(acc, 0.0f);
    }
    flag_signal(&flags[F_C2]);
    return;
  }

  // ================================================================ conv3 + maxpool (160 blocks)
  else if (bid < RB_PW) {
    flag_wait(&flags[F_C2], NB_C2, 4);
    const int q = bid - RB_C3;
    const int b2 = q % 32, ot = q / 32;
    float* il = sm.c3.il;
    float* wl = sm.c3.wl;
    float* o3 = sm.c3.o3;
    const int tid = threadIdx.x;
    for (int idx = tid; idx < C_ * 45; idx += 256) il[idx] = out2[(size_t)b2 * C_ * 45 + idx];
    int obase = ot * 20;
    for (int idx = tid; idx < 20 * 500; idx += 256) wl[idx] = conv3_w[obase * 500 + idx];
    __syncthreads();
    for (int idx = tid; idx < 20 * 41; idx += 256) {
      int o = idx / 41, t2 = idx % 41;
      float acc = conv3_b[obase + o];
      const float* wr = &wl[o * 500];
      for (int c = 0; c < C_; ++c) {
        const float* ip = &il[c * 45 + t2];
        acc += wr[c * 5 + 0] * ip[0] + wr[c * 5 + 1] * ip[1] + wr[c * 5 + 2] * ip[2] +
               wr[c * 5 + 3] * ip[3] + wr[c * 5 + 4] * ip[4];
      }
      o3[o * 44 + t2] = fmaxf(acc, 0.0f);
    }
    __syncthreads();
    if (tid < 20) {
      float m = o3[tid * 44];
      for (int t2 = 1; t2 < 41; ++t2) m = fmaxf(m, o3[tid * 44 + t2]);
      pooled[b2 * C_ + obase + tid] = m;
    }
    flag_signal(&flags[F_C3]);
    return;
  }

  // ================================================================ prep_w (64 blocks, strided)
  else if (bid < RB_PB) {
    const int q = bid - RB_PW;
    const int total = 2 * G4_ * KP_;
    for (int idx = q * 256 + (int)threadIdx.x; idx < total; idx += NB_PW * 256) {
      int d = idx / (G4_ * KP_);
      int rem = idx % (G4_ * KP_);
      int j = rem / KP_, k2 = rem % KP_;
      const float* w2 = d ? w_ih_b : w_ih_f;
      float v0 = 0.f, v1 = 0.f;
      if (k2 < 200) { v0 = w2[(size_t)j * DHID_ + 2 * k2]; v1 = w2[(size_t)j * DHID_ + 2 * k2 + 1]; }
      unsigned p0 = pack_split(v0), p1 = pack_split(v1);
      apH[idx] = (p0 & 0xFFFFu) | (p1 << 16);
      apL[idx] = (p0 >> 16) | (p1 & 0xFFFF0000u);
    }
    flag_signal(&flags[F_PW]);
    return;
  }

  // ================================================================ prep_b (512 blocks × 8 rows)
  else if (bid < RB_GEMM) {
    flag_wait(&flags[F_C3], NB_C3, 8);
    const int q = bid - RB_PB;
    const int tid = threadIdx.x;
    if (tid < KP_) {
      int k2 = tid;
      for (int rr = 0; rr < 8; ++rr) {
        int r = q * 8 + rr;
        int t2 = r >> 5, b2 = r & 31;
        float v0 = 0.f, v1 = 0.f;
        if (k2 < 150) {
          const float* e2 = word_emb + (size_t)x[b2 * S_ + t2] * E_;
          v0 = e2[2 * k2]; v1 = e2[2 * k2 + 1];
        } else if (k2 < 200) {
          v0 = pooled[b2 * C_ + 2 * k2 - 300];
          v1 = pooled[b2 * C_ + 2 * k2 - 299];
        }
        unsigned p0 = pack_split(v0), p1 = pack_split(v1);
        bpH[(size_t)r * KP_ + k2] = (p0 & 0xFFFFu) | (p1 << 16);
        bpL[(size_t)r * KP_ + k2] = (p0 >> 16) | (p1 & 0xFFFF0000u);
      }
    }
    flag_signal(&flags[F_PB]);
    return;
  }

  // ================================================================ input GEMM (512 blocks)
  else if (bid < RB_FC) {
    flag_wait(&flags[F_PW], NB_PW, 16);
    flag_wait(&flags[F_PB], NB_PB, 16);
    const int q = bid - RB_GEMM;
    // d fastest; backward direction consumes t descending -> give it rt descending
    const int d = q & 1;
    const int jt = (q >> 1) & 7;
    const int rtb = q >> 4;
    const int rt = d ? (31 - rtb) : rtb;
    const int j0 = jt * 128, r0 = rt * 128;
    const int tid = threadIdx.x;
    const int w = tid >> 6, l = tid & 63;
    const int lx = l & 15, lq = l >> 4;

    unsigned* aH = sm.gemm.aH;
    unsigned* aL = sm.gemm.aL;
    unsigned* bH = sm.gemm.bH;
    unsigned* bL = sm.gemm.bL;

    f32x4 acch[2][8], accl[2][8];
#pragma unroll
    for (int mt = 0; mt < 2; ++mt)
#pragma unroll
      for (int nt = 0; nt < 8; ++nt) {
        f32x4 z = {0.f, 0.f, 0.f, 0.f};
        acch[mt][nt] = z; accl[mt][nt] = z;
      }

    const int jr = tid >> 1, hh = tid & 1;
    const int q_st = jr >> 4, lane_lo = jr & 15;
    const unsigned* arH = apH + ((size_t)(d * G4_ + j0 + jr)) * KP_ + hh * 8;
    const unsigned* arL = apL + ((size_t)(d * G4_ + j0 + jr)) * KP_ + hh * 8;
    const unsigned* brH = bpH + ((size_t)(r0 + jr)) * KP_ + hh * 8;
    const unsigned* brL = bpL + ((size_t)(r0 + jr)) * KP_ + hh * 8;
    const int w0 = (q_st * 64 + lane_lo + 32 * hh) * 4;
    const int w1 = (q_st * 64 + lane_lo + 32 * hh + 16) * 4;

    for (int Kt = 0; Kt < 13; ++Kt) {
      uint4 a0 = *(const uint4*)(arH + Kt * 16);
      uint4 a1 = *(const uint4*)(arH + Kt * 16 + 4);
      uint4 c0v = *(const uint4*)(arL + Kt * 16);
      uint4 c1v = *(const uint4*)(arL + Kt * 16 + 4);
      uint4 e0 = *(const uint4*)(brH + Kt * 16);
      uint4 e1 = *(const uint4*)(brH + Kt * 16 + 4);
      uint4 f0 = *(const uint4*)(brL + Kt * 16);
      uint4 f1 = *(const uint4*)(brL + Kt * 16 + 4);
      *(uint4*)&aH[w0] = a0; *(uint4*)&aH[w1] = a1;
      *(uint4*)&aL[w0] = c0v; *(uint4*)&aL[w1] = c1v;
      *(uint4*)&bH[w0] = e0; *(uint4*)&bH[w1] = e1;
      *(uint4*)&bL[w0] = f0; *(uint4*)&bL[w1] = f1;
      __syncthreads();

      union u4h { uint4 u; half8 h; };
      u4h AH0, AH1, AL0, AL1;
      AH0.u = *(const uint4*)&aH[((2 * w + 0) * 64 + l) * 4];
      AH1.u = *(const uint4*)&aH[((2 * w + 1) * 64 + l) * 4];
      AL0.u = *(const uint4*)&aL[((2 * w + 0) * 64 + l) * 4];
      AL1.u = *(const uint4*)&aL[((2 * w + 1) * 64 + l) * 4];
#pragma unroll
      for (int nt = 0; nt < 8; ++nt) {
        u4h BHn, BLn;
        BHn.u = *(const uint4*)&bH[(nt * 64 + l) * 4];
        BLn.u = *(const uint4*)&bL[(nt * 64 + l) * 4];
        acch[0][nt] = __builtin_amdgcn_mfma_f32_16x16x32_f16(AH0.h, BHn.h, acch[0][nt], 0, 0, 0);
        accl[0][nt] = __builtin_amdgcn_mfma_f32_16x16x32_f16(AH0.h, BLn.h, accl[0][nt], 0, 0, 0);
        accl[0][nt] = __builtin_amdgcn_mfma_f32_16x16x32_f16(AL0.h, BHn.h, accl[0][nt], 0, 0, 0);
        acch[1][nt] = __builtin_amdgcn_mfma_f32_16x16x32_f16(AH1.h, BHn.h, acch[1][nt], 0, 0, 0);
        accl[1][nt] = __builtin_amdgcn_mfma_f32_16x16x32_f16(AH1.h, BLn.h, accl[1][nt], 0, 0, 0);
        accl[1][nt] = __builtin_amdgcn_mfma_f32_16x16x32_f16(AL1.h, BHn.h, accl[1][nt], 0, 0, 0);
      }
      __syncthreads();
    }

    const float* bias = d ? b_b : b_f;
    const float inv2048 = 1.0f / 2048.0f;
#pragma unroll
    for (int mt = 0; mt < 2; ++mt) {
#pragma unroll
      for (int nt = 0; nt < 8; ++nt) {
        int rr = r0 + nt * 16 + lx;
        int tt = rr >> 5, bb2 = rr & 31;
        unsigned* dst = (unsigned*)gi + ((size_t)(d * S_ + tt) * G4_) * B_ + bb2;
#pragma unroll
        for (int r4 = 0; r4 < 4; ++r4) {
          int j = j0 + (2 * w + mt) * 16 + lq * 4 + r4;
          float vv = acch[mt][nt][r4] + accl[mt][nt][r4] * inv2048 + bias[j];
          __hip_atomic_store(&dst[(size_t)j * B_], __builtin_bit_cast(unsigned, vv),
                             __ATOMIC_RELAXED, __HIP_MEMORY_SCOPE_AGENT);
        }
      }
    }
    return;
  }

  // ================================================================ FC -> emissions (128 blocks)
  else if (bid < RB_SMV) {
    const int s = bid - RB_FC;
    const int tid = threadIdx.x;
    float* wT = sm.fc.wT;
    float* psum = sm.fc.psum;
    for (int i = tid; i < L_ * 512; i += 256) {
      int l2 = i / 512, k = i % 512;
      wT[k * 18 + l2] = fc_w[i];
    }
    const float* hf = hbuf + (size_t)(s + 1) * (H_ * B_);
    const float* hbk = hbuf + (size_t)(S_ + 1 + (S_ - s)) * (H_ * B_);
    const unsigned* hfu = (const unsigned*)hf;
    const unsigned* hbku = (const unsigned*)hbk;
    // cheap proxy poll (1 broadcast word per direction) while the lstm runs
    for (;;) {
      unsigned a = __hip_atomic_load(&hfu[0], __ATOMIC_RELAXED, __HIP_MEMORY_SCOPE_AGENT);
      unsigned c = __hip_atomic_load(&hbku[0], __ATOMIC_RELAXED, __HIP_MEMORY_SCOPE_AGENT);
      if (a != SENTF_ && c != SENTF_) break;
      __builtin_amdgcn_s_sleep(32);
    }
    const int b2 = tid & 31, kq = tid >> 5;
    const unsigned* basep = (kq < 4) ? hfu : hbku;
    const int koff = (kq < 4) ? kq * 64 : kq * 64 - 256;
    unsigned hraw[64];
    for (;;) {
      bool pend = false;
#pragma unroll
      for (int i = 0; i < 64; ++i)
        hraw[i] = __hip_atomic_load(&basep[(size_t)(koff + i) * 32 + b2],
                                    __ATOMIC_RELAXED, __HIP_MEMORY_SCOPE_AGENT);
#pragma unroll
      for (int i = 0; i < 64; ++i) pend |= (hraw[i] == SENTF_);
      if (!pend) break;
      __builtin_amdgcn_s_sleep(8);
    }
    __syncthreads();
    float acc[L_];
#pragma unroll
    for (int l2 = 0; l2 < L_; ++l2) acc[l2] = 0.f;
#pragma unroll
    for (int i = 0; i < 64; ++i) {
      int k = kq * 64 + i;
      float hv = __builtin_bit_cast(float, hraw[i]);
      const float* wr = &wT[k * 18];
#pragma unroll
      for (int l2 = 0; l2 < L_; ++l2) acc[l2] = fmaf(hv, wr[l2], acc[l2]);
    }
#pragma unroll
    for (int l2 = 0; l2 < L_; ++l2) psum[tid * 18 + l2] = acc[l2];
    __syncthreads();
    for (int idx = tid; idx < B_ * L_; idx += 256) {
      int bb2 = idx & 31, l2 = idx >> 5;
      float sum = fc_b[l2];
      for (int q2 = 0; q2 < 8; ++q2) sum += psum[(q2 * 32 + bb2) * 18 + l2];
      __hip_atomic_store((unsigned*)&em[((size_t)bb2 * S_ + s) * L_ + l2],
                         __builtin_bit_cast(unsigned, sum),
                         __ATOMIC_RELAXED, __HIP_MEMORY_SCOPE_AGENT);
    }
    return;
  }

  // ================================================================ softmax + viterbi (32 blocks)
  else {
    const int bb = bid - RB_SMV;
    const int tid = threadIdx.x;
    float* e = sm.smv.e;
    float* tr = sm.smv.tr;
    auto sc = sm.smv.sc;
    int* hist = sm.smv.hist;
    int* tags = sm.smv.tags;

    int ei[9];
#pragma unroll
    for (int j = 0; j < 9; ++j) { int i = tid + j * 256; ei[j] = (i < S_ * L_) ? i : tid; }
    const unsigned* emu = (const unsigned*)em + (size_t)bb * S_ * L_;
    unsigned ev[9];
    for (;;) {
      bool pend = false;
#pragma unroll
      for (int j = 0; j < 9; ++j)
        ev[j] = __hip_atomic_load(&emu[ei[j]], __ATOMIC_RELAXED, __HIP_MEMORY_SCOPE_AGENT);
#pragma unroll
      for (int j = 0; j < 9; ++j) pend |= (ev[j] == SENTF_);
      if (!pend) break;
      __builtin_amdgcn_s_sleep(127);
    }
#pragma unroll
    for (int j = 0; j < 9; ++j) e[ei[j]] = __builtin_bit_cast(float, ev[j]);
    for (int i = tid; i < L_ * L_; i += 256) tr[i] = trans[i];
    __syncthreads();
    if (tid < L_) {
      int l2 = tid;
      float m = -INFINITY;
      for (int s2 = 0; s2 < S_; ++s2) m = fmaxf(m, e[s2 * L_ + l2]);
      float sum2 = 0.f;
      for (int s2 = 0; s2 < S_; ++s2) {
        float ex = expf(e[s2 * L_ + l2] - m);
        e[s2 * L_ + l2] = ex;
        sum2 += ex;
      }
      for (int s2 = 0; s2 < S_; ++s2) e[s2 * L_ + l2] = e[s2 * L_ + l2] / sum2;
    }
    __syncthreads();
    if (tid < L_) sc[0][tid] = start_t[tid] + e[tid];
    __syncthreads();
    int cbuf = 0;
    for (int t2 = 1; t2 < S_; ++t2) {
      if (tid < L_) {
        int j2 = tid;
        float evv = e[t2 * L_ + j2];
        float best = -INFINITY;
        int arg = 0;
        for (int i = 0; i < L_; ++i) {
          float v = (sc[cbuf][i] + tr[i * L_ + j2]) + evv;
          if (v > best) { best = v; arg = i; }  // strict >: first occurrence like np.argmax
        }
        int maskt = (x[bb * S_ + t2] != 0);
        sc[cbuf ^ 1][j2] = maskt ? best : sc[cbuf][j2];
        hist[(t2 - 1) * L_ + j2] = arg;
      }
      __syncthreads();
      cbuf ^= 1;
    }
    if (tid == 0) {
      float best = -INFINITY;
      int last = 0;
      for (int j2 = 0; j2 < L_; ++j2) {
        float v = sc[cbuf][j2] + end_t[j2];
        if (v > best) { best = v; last = j2; }
      }
      int cur = last;
      tags[S_ - 1] = cur;
      for (int p = S_ - 2; p >= 0; --p) {
        if (x[bb * S_ + p + 1] != 0) cur = hist[p * L_ + cur];
        tags[p] = cur;
      }
    }
    __syncthreads();
    for (int s2 = tid; s2 < S_; s2 += 256) out[bb * S_ + s2] = tags[s2];
    return;
  }
}

// ---------------------------------------------------------------- launch
extern "C" void kernel_launch(void* const* d_in, const int* in_sizes, int n_in,
                              void* d_out, int out_size, void* d_ws, size_t ws_size,
                              hipStream_t stream) {
  const int* x        = (const int*)d_in[0];
  const int* x_char   = (const int*)d_in[1];
  const float* word_emb = (const float*)d_in[2];
  const float* char_emb = (const float*)d_in[3];
  const float* conv1_w = (const float*)d_in[4];
  const float* conv1_b = (const float*)d_in[5];
  const float* conv2_w = (const float*)d_in[6];
  const float* conv2_b = (const float*)d_in[7];
  const float* conv3_w = (const float*)d_in[8];
  const float* conv3_b = (const float*)d_in[9];
  const float* w_ih_f = (const float*)d_in[10];
  const float* w_hh_f = (const float*)d_in[11];
  const float* b_f    = (const float*)d_in[12];
  const float* w_ih_b = (const float*)d_in[13];
  const float* w_hh_b = (const float*)d_in[14];
  const float* b_b    = (const float*)d_in[15];
  const float* h0     = (const float*)d_in[16];
  const float* c0     = (const float*)d_in[17];
  const float* fc_w   = (const float*)d_in[18];
  const float* fc_b   = (const float*)d_in[19];
  const float* start_t = (const float*)d_in[20];
  const float* trans  = (const float*)d_in[21];
  const float* end_t  = (const float*)d_in[22];
  int* out = (int*)d_out;

  char* ws = (char*)d_ws;
  auto alloc = [&](size_t bytes) -> char* {
    char* p = ws;
    ws += (bytes + 1023) & ~(size_t)1023;
    return p;
  };
  float* pooled  = (float*)alloc(sizeof(float) * B_ * C_);
  float* gi      = (float*)alloc(sizeof(float) * 2 * S_ * G4_ * B_);
  float* hbuf    = (float*)alloc(sizeof(float) * 2 * (S_ + 1) * H_ * B_);
  unsigned* hfrag = (unsigned*)alloc(sizeof(unsigned) * 2 * (S_ + 1) * SLAB_);
  unsigned* apH  = (unsigned*)alloc(sizeof(unsigned) * 2 * G4_ * KP_);
  unsigned* apL  = (unsigned*)alloc(sizeof(unsigned) * 2 * G4_ * KP_);
  unsigned* bpH  = (unsigned*)alloc(sizeof(unsigned) * 4096 * KP_);
  unsigned* bpL  = (unsigned*)alloc(sizeof(unsigned) * 4096 * KP_);
  float* out1    = (float*)alloc(sizeof(float) * B_ * C_ * 48);
  float* out2    = (float*)alloc(sizeof(float) * B_ * C_ * 45);
  float* em      = (float*)alloc(sizeof(float) * B_ * S_ * L_);
  int* flags     = (int*)alloc(sizeof(int) * 16);

  k_fill<<<2048, 256, 0, stream>>>(h0, hfrag, (unsigned*)hbuf, (unsigned*)gi,
                                   (unsigned*)em, flags);
  k_mega<<<NBLK_MEGA, 256, 0, stream>>>(
      x, x_char, word_emb, char_emb,
      conv1_w, conv1_b, conv2_w, conv2_b, conv3_w, conv3_b,
      w_ih_f, w_ih_b, w_hh_f, w_hh_b, b_f, b_b, c0, fc_w, fc_b,
      start_t, trans, end_t,
      pooled, gi, hbuf, hfrag, apH, apL, bpH, bpL, out1, out2, em, flags, out);
}

// Round 2
// 1106.537 us; speedup vs baseline: 1.5186x; 1.5186x over previous
//
#include <hip/hip_runtime.h>
#include <cmath>

#define B_   32
#define S_   128
#define E_   300
#define C_   100
#define EC_  50
#define LC_  50
#define H_   256
#define G4_  1024   // 4*H
#define L_   17
#define DHID_ 400   // E + C
#define NBLKD 8     // lstm blocks per direction
#define SLAB_ 8192  // u32 per (d,t) frag slab: [Nt(2)][Kt(8)][lane(64)][hi m0..3 | lo m4..7]
#define SENT2_ 0x7E007E00u  // fp16-NaN in both halves: legit packed pair never matches
#define SENTF_ 0x7FC0DEADu  // fp32 qNaN sentinel: legit finite result never matches
#define KP_   208   // k-pairs per row in packed GEMM operands (416 k, zero-padded from 400)

// ---- mega-kernel role layout (dispatch order = dependency-safe order) ----
#define RB_LSTM 0
#define NB_LSTM 16
#define RB_C1   16
#define NB_C1   64
#define RB_C2   80
#define NB_C2   128
#define RB_C3   208
#define NB_C3   160
#define RB_PW   368
#define NB_PW   64
#define RB_PB   432
#define NB_PB   512
#define RB_GEMM 944
#define NB_GEMM 512
#define RB_FC   1456
#define NB_FC   128
#define RB_SMV  1584
#define NB_SMV  32
#define NBLK_MEGA 1616

#define F_C1 0
#define F_C2 1
#define F_C3 2
#define F_PW 3
#define F_PB 4

typedef _Float16 half8 __attribute__((ext_vector_type(8)));
typedef float f32x4 __attribute__((ext_vector_type(4)));
typedef unsigned long long ull;
struct __align__(16) U2 { ull x, y; };

// split fp32 -> (hi fp16, lo fp16 scaled by 2048), packed u32 (hi in low16).
__device__ __forceinline__ unsigned pack_split(float v) {
  _Float16 hi = (fabsf(v) >= 6.104e-5f) ? (_Float16)v : (_Float16)0.0f;
  float hif = (float)hi;
  _Float16 lo = (_Float16)((v - hif) * 2048.0f);
  return (unsigned)__builtin_bit_cast(unsigned short, hi)
       | ((unsigned)__builtin_bit_cast(unsigned short, lo) << 16);
}

__device__ __forceinline__ void flag_signal(int* f) {
  __syncthreads();   // all threads' plain stores drained (waitcnt before s_barrier)
  if (threadIdx.x == 0)
    __hip_atomic_fetch_add(f, 1, __ATOMIC_RELEASE, __HIP_MEMORY_SCOPE_AGENT);
}
__device__ __forceinline__ void flag_wait(const int* f, int target, int slp) {
  while (__hip_atomic_load(f, __ATOMIC_ACQUIRE, __HIP_MEMORY_SCOPE_AGENT) < target) {
    switch (slp) {
      case 4:  __builtin_amdgcn_s_sleep(4);  break;
      case 8:  __builtin_amdgcn_s_sleep(8);  break;
      default: __builtin_amdgcn_s_sleep(16); break;
    }
  }
}

// LDS union: one static allocation, role-dependent view. Max member = conv3 (61.5 KB).
union SMem {
  struct { unsigned aH[2048], aL[2048], bH[2048], bL[2048]; } gemm;                     // 32 KB
  struct { ull slh[2048], sll[2048]; float gl[4 * 32 * 33]; unsigned ps[2 * 576]; } lstm; // 54.2 KB
  struct { float ce[EC_ * 52]; float wl[50 * 150]; int ids[LC_]; } c1;
  struct { float il[C_ * 48]; float wl[25 * 400]; } c2;                                  // 59.2 KB
  struct { float il[C_ * 45]; float wl[20 * 500]; float o3[20 * 44]; } c3;               // 61.5 KB
  struct { float wT[512 * 18]; float psum[256 * 18]; } fc;                               // 55.3 KB
  struct { float e[S_ * L_]; float tr[L_ * L_]; float sc[2][L_];
           int hist[(S_ - 1) * L_]; int tags[S_]; } smv;
};

// ---------------------------------------------------------------- fill: hfrag init + sentinels + flags
__global__ void k_fill(const float* __restrict__ h0, unsigned* __restrict__ hfrag,
                       unsigned* __restrict__ hbufU, unsigned* __restrict__ giU,
                       unsigned* __restrict__ emU, int* __restrict__ flags) {
  const int g0 = blockIdx.x * 256 + threadIdx.x;
  const int nth = gridDim.x * 256;
  // hfrag: t=0 packed from h0, t>=1 sentinel (identical to previous k_hinit)
  const int htot = 2 * (S_ + 1) * SLAB_;
  for (int idx = g0; idx < htot; idx += nth) {
    int sd = idx / SLAB_;
    int within = idx % SLAB_;
    int t = sd % (S_ + 1), d = sd / (S_ + 1);
    if (t != 0) { hfrag[idx] = SENT2_; continue; }
    int m8 = within & 7;
    int lane = (within >> 3) & 63;
    int q = within >> 9;
    int Kt = q & 7, Nt = q >> 3;
    int m = m8 & 3, isLo = m8 >> 2;
    int k0 = Kt * 32 + (lane >> 4) * 8 + 2 * m;
    int b = Nt * 16 + (lane & 15);
    unsigned p0 = pack_split(h0[((size_t)d * B_ + b) * H_ + k0]);
    unsigned p1 = pack_split(h0[((size_t)d * B_ + b) * H_ + k0 + 1]);
    unsigned hiw = (p0 & 0xFFFFu) | (p1 << 16);
    unsigned low = (p0 >> 16) | (p1 & 0xFFFF0000u);
    hfrag[idx] = isLo ? low : hiw;
  }
  const int hbtot = 2 * (S_ + 1) * H_ * B_;
  for (int idx = g0; idx < hbtot; idx += nth) hbufU[idx] = SENTF_;
  const int gtot = 2 * S_ * G4_ * B_;
  for (int idx = g0; idx < gtot; idx += nth) giU[idx] = SENTF_;
  const int etot = B_ * S_ * L_;
  for (int idx = g0; idx < etot; idx += nth) emU[idx] = SENTF_;
  if (g0 < 16) flags[g0] = 0;
}

// ---------------------------------------------------------------- mega: all stages, one launch
// NOTE: no min-waves clause. R1's __launch_bounds__(256,2) capped VGPRs at 128 while the
// LSTM branch needs ~144 -> ~22 regs spilled/filled per timestep ON the recurrence critical
// path (WRITE_SIZE 16->62 MB, FETCH +44 MB, k_lstm-equivalent 3.9 -> ~12 us/step).
__global__ __launch_bounds__(256) void k_mega(
    const int* __restrict__ x, const int* __restrict__ x_char,
    const float* __restrict__ word_emb, const float* __restrict__ char_emb,
    const float* __restrict__ conv1_w, const float* __restrict__ conv1_b,
    const float* __restrict__ conv2_w, const float* __restrict__ conv2_b,
    const float* __restrict__ conv3_w, const float* __restrict__ conv3_b,
    const float* __restrict__ w_ih_f, const float* __restrict__ w_ih_b,
    const float* __restrict__ w_hh_f, const float* __restrict__ w_hh_b,
    const float* __restrict__ b_f, const float* __restrict__ b_b,
    const float* __restrict__ c0,
    const float* __restrict__ fc_w, const float* __restrict__ fc_b,
    const float* __restrict__ start_t, const float* __restrict__ trans,
    const float* __restrict__ end_t,
    float* __restrict__ pooled, float* __restrict__ gi, float* __restrict__ hbuf,
    unsigned* __restrict__ hfrag,
    unsigned* __restrict__ apH, unsigned* __restrict__ apL,
    unsigned* __restrict__ bpH, unsigned* __restrict__ bpL,
    float* __restrict__ out1, float* __restrict__ out2,
    float* __restrict__ em, int* __restrict__ flags, int* __restrict__ out) {
  const int bid = blockIdx.x;
  __shared__ SMem sm;

  // ================================================================ LSTM (bids 0..15)
  if (bid < RB_C1) {
    __builtin_amdgcn_s_setprio(2);  // recurrence is the critical path; win CU arbitration
    const int iblk = bid & 7;
    const int d = bid >> 3;
    const float* whh = d ? w_hh_b : w_hh_f;
    const int tid = threadIdx.x;
    const int w = tid >> 6;          // wave index = gate (i,f,g,o)
    const int l = tid & 63;
    const int lx = l & 15, lq = l >> 4;
    const int u0 = iblk * 32;

    ull* slh = sm.lstm.slh;
    ull* sll = sm.lstm.sll;
    float* glb = sm.lstm.gl;
    unsigned* ps = sm.lstm.ps;

    half8 whi[2][8], wlo[2][8];
#pragma unroll
    for (int Mt = 0; Mt < 2; ++Mt) {
#pragma unroll
      for (int Kt = 0; Kt < 8; ++Kt) {
        int row = w * H_ + u0 + Mt * 16 + lx;
        int kk0 = Kt * 32 + lq * 8;
        const float* src = whh + (size_t)row * H_ + kk0;
        float4 f0 = *(const float4*)src;
        float4 f1 = *(const float4*)(src + 4);
        float wv[8] = {f0.x, f0.y, f0.z, f0.w, f1.x, f1.y, f1.z, f1.w};
        union { unsigned short s2[8]; half8 h; } HI, LO;
#pragma unroll
        for (int j = 0; j < 8; ++j) {
          float v = wv[j];
          _Float16 hi = (fabsf(v) >= 6.104e-5f) ? (_Float16)v : (_Float16)0.0f;
          float hif = (float)hi;
          _Float16 lo = (_Float16)((v - hif) * 2048.0f);
          HI.s2[j] = __builtin_bit_cast(unsigned short, hi);
          LO.s2[j] = __builtin_bit_cast(unsigned short, lo);
        }
        whi[Mt][Kt] = HI.h;
        wlo[Mt][Kt] = LO.h;
      }
    }

    const int bc = tid & 31, cw = tid >> 5;
    float creg[4];
#pragma unroll
    for (int cu = 0; cu < 4; ++cu)
      creg[cu] = c0[((size_t)d * B_ + bc) * H_ + u0 + cu * 8 + cw];

    const int pNt = bc >> 4;
    const int pm = cw >> 1;
    const bool phi = (cw & 1) == 0;
    const int plane = bc & 15;
    const float inv2048 = 1.0f / 2048.0f;

    for (int t = 0; t < S_; ++t) {
      int torig = d ? (S_ - 1 - t) : t;

      // gi loads issued first (sentinel-gated; ready in steady state — check deferred
      // until after the hfrag spin so their latency hides under it)
      const unsigned* gbase = (const unsigned*)gi + ((size_t)(d * S_ + torig) * G4_) * B_;
      unsigned gv[2][2][4];
#pragma unroll
      for (int Mt = 0; Mt < 2; ++Mt)
#pragma unroll
        for (int Nt = 0; Nt < 2; ++Nt)
#pragma unroll
          for (int r = 0; r < 4; ++r) {
            int j = w * H_ + u0 + Mt * 16 + lq * 4 + r;
            gv[Mt][Nt][r] = __hip_atomic_load(&gbase[(size_t)j * B_ + Nt * 16 + lx],
                                              __ATOMIC_RELAXED, __HIP_MEMORY_SCOPE_AGENT);
          }

      // spin on previous-step h fragments (unchanged protocol)
      const ull* hp = (const ull*)(hfrag + (size_t)(d * (S_ + 1) + t) * SLAB_);
      ull pv[4][4];
#pragma unroll
      for (int c = 0; c < 4; ++c) {
        size_t base = ((size_t)(w * 4 + c) * 64 + l) * 4;
#pragma unroll
        for (int j = 0; j < 4; ++j)
          pv[c][j] = __hip_atomic_load(&hp[base + j], __ATOMIC_RELAXED,
                                       __HIP_MEMORY_SCOPE_AGENT);
      }
      for (;;) {
        bool pending = false;
#pragma unroll
        for (int c = 0; c < 4; ++c)
#pragma unroll
          for (int j = 0; j < 4; ++j)
            pending |= ((unsigned)pv[c][j] == SENT2_) |
                       ((unsigned)(pv[c][j] >> 32) == SENT2_);
        if (!pending) break;
#pragma unroll
        for (int c = 0; c < 4; ++c) {
          size_t base = ((size_t)(w * 4 + c) * 64 + l) * 4;
#pragma unroll
          for (int j = 0; j < 4; ++j)
            pv[c][j] = __hip_atomic_load(&hp[base + j], __ATOMIC_RELAXED,
                                         __HIP_MEMORY_SCOPE_AGENT);
        }
      }

      // gi sentinel check (rare retries — only while gemm is still ahead of us)
      for (;;) {
        bool pending = false;
#pragma unroll
        for (int Mt = 0; Mt < 2; ++Mt)
#pragma unroll
          for (int Nt = 0; Nt < 2; ++Nt)
#pragma unroll
            for (int r = 0; r < 4; ++r) pending |= (gv[Mt][Nt][r] == SENTF_);
        if (!pending) break;
#pragma unroll
        for (int Mt = 0; Mt < 2; ++Mt)
#pragma unroll
          for (int Nt = 0; Nt < 2; ++Nt)
#pragma unroll
            for (int r = 0; r < 4; ++r) {
              int j = w * H_ + u0 + Mt * 16 + lq * 4 + r;
              gv[Mt][Nt][r] = __hip_atomic_load(&gbase[(size_t)j * B_ + Nt * 16 + lx],
                                                __ATOMIC_RELAXED, __HIP_MEMORY_SCOPE_AGENT);
            }
      }

      f32x4 acch[2][2], accl[2][2];
#pragma unroll
      for (int Mt = 0; Mt < 2; ++Mt)
#pragma unroll
        for (int Nt = 0; Nt < 2; ++Nt) {
          f32x4 v, z = {0.f, 0.f, 0.f, 0.f};
#pragma unroll
          for (int r = 0; r < 4; ++r) v[r] = __builtin_bit_cast(float, gv[Mt][Nt][r]);
          acch[Mt][Nt] = v;
          accl[Mt][Nt] = z;
        }

#pragma unroll
      for (int c = 0; c < 4; ++c) {
        int idx = ((w * 4 + c) * 64 + l) * 2;
        U2 vh; vh.x = pv[c][0]; vh.y = pv[c][1];
        U2 vl; vl.x = pv[c][2]; vl.y = pv[c][3];
        *(U2*)&slh[idx] = vh;
        *(U2*)&sll[idx] = vl;
      }
      __syncthreads();

#pragma unroll
      for (int Kt = 0; Kt < 8; ++Kt) {
        half8 Bhi[2], Blo[2];
#pragma unroll
        for (int Nt = 0; Nt < 2; ++Nt) {
          int idx = ((Nt * 8 + Kt) * 64 + l) * 2;
          union { U2 u; half8 h; } UH, UL;
          UH.u = *(const U2*)&slh[idx];
          UL.u = *(const U2*)&sll[idx];
          Bhi[Nt] = UH.h;
          Blo[Nt] = UL.h;
        }
#pragma unroll
        for (int Mt = 0; Mt < 2; ++Mt)
#pragma unroll
          for (int Nt = 0; Nt < 2; ++Nt) {
            acch[Mt][Nt] = __builtin_amdgcn_mfma_f32_16x16x32_f16(
                whi[Mt][Kt], Bhi[Nt], acch[Mt][Nt], 0, 0, 0);
            accl[Mt][Nt] = __builtin_amdgcn_mfma_f32_16x16x32_f16(
                whi[Mt][Kt], Blo[Nt], accl[Mt][Nt], 0, 0, 0);
            accl[Mt][Nt] = __builtin_amdgcn_mfma_f32_16x16x32_f16(
                wlo[Mt][Kt], Bhi[Nt], accl[Mt][Nt], 0, 0, 0);
          }
      }

#pragma unroll
      for (int Mt = 0; Mt < 2; ++Mt)
#pragma unroll
        for (int Nt = 0; Nt < 2; ++Nt)
#pragma unroll
          for (int r = 0; r < 4; ++r) {
            int ul = Mt * 16 + lq * 4 + r;
            glb[(w * 32 + ul) * 33 + Nt * 16 + lx] =
                acch[Mt][Nt][r] + accl[Mt][Nt][r] * inv2048;
          }
      __syncthreads();

      float hreg[4];
#pragma unroll
      for (int cu = 0; cu < 4; ++cu) {
        int u = cu * 8 + cw;
        float g_i = glb[(0 * 32 + u) * 33 + bc];
        float g_f = glb[(1 * 32 + u) * 33 + bc];
        float g_g = glb[(2 * 32 + u) * 33 + bc];
        float g_o = glb[(3 * 32 + u) * 33 + bc];
        float si = 1.f / (1.f + __expf(-g_i));
        float sf = 1.f / (1.f + __expf(-g_f));
        float so = 1.f / (1.f + __expf(-g_o));
        float tg = 1.f - 2.f / (__expf(2.f * g_g) + 1.f);
        float cn = sf * creg[cu] + si * tg;
        float tc = 1.f - 2.f / (__expf(2.f * cn) + 1.f);
        float hn = so * tc;
        creg[cu] = cn;
        hreg[cu] = hn;
        unsigned me = pack_split(hn);
        unsigned pa = (unsigned)__shfl_xor((int)me, 32, 64);
        unsigned je = (cw & 1) ? pa : me;
        unsigned jo = (cw & 1) ? me : pa;
        unsigned hiw = (je & 0xFFFFu) | (jo << 16);
        unsigned low = (je >> 16) | (jo & 0xFFFF0000u);
        int lane2 = (cu << 4) | plane;
        int m8 = phi ? pm : (4 + pm);
        ps[pNt * 576 + lane2 * 9 + m8] = phi ? hiw : low;
      }
      __syncthreads();

      {
        ull* slab64 = (ull*)(hfrag + (size_t)(d * (S_ + 1) + t + 1) * SLAB_);
#pragma unroll
        for (int hh2 = 0; hh2 < 2; ++hh2) {
          int r = tid;
          int Nt = hh2;
          int lane2 = r >> 2, m2 = r & 3;
          unsigned a = ps[Nt * 576 + lane2 * 9 + 2 * m2];
          unsigned b2 = ps[Nt * 576 + lane2 * 9 + 2 * m2 + 1];
          ull v = (ull)a | ((ull)b2 << 32);
          __hip_atomic_store(&slab64[(size_t)(Nt * 8 + iblk) * 256 + r], v,
                             __ATOMIC_RELAXED, __HIP_MEMORY_SCOPE_AGENT);
        }
        // hbuf now published with device-visible relaxed stores (fc polls it)
        float* hb = hbuf + (size_t)(d * (S_ + 1) + t + 1) * (H_ * B_) + u0 * B_;
#pragma unroll
        for (int cu = 0; cu < 4; ++cu)
          __hip_atomic_store(&hb[cu * 256 + tid], hreg[cu],
                             __ATOMIC_RELAXED, __HIP_MEMORY_SCOPE_AGENT);
      }
    }
    return;
  }

  // ================================================================ conv1 (64 blocks)
  else if (bid < RB_C2) {
    const int q = bid - RB_C1;
    const int b2 = q & 31, ot = q >> 5;
    float* ce = sm.c1.ce;
    float* wl = sm.c1.wl;
    int* ids = sm.c1.ids;
    const int tid = threadIdx.x;
    if (tid < LC_) ids[tid] = x_char[b2 * LC_ + tid];
    __syncthreads();
    for (int idx = tid; idx < LC_ * EC_; idx += 256) {
      int t2 = idx / EC_, ec = idx % EC_;
      ce[ec * 52 + t2] = char_emb[ids[t2] * EC_ + ec];
    }
    int obase = ot * 50;
    for (int idx = tid; idx < 50 * 150; idx += 256)
      wl[idx] = conv1_w[obase * 150 + idx];
    __syncthreads();
    for (int idx = tid; idx < 50 * 48; idx += 256) {
      int o = idx / 48, t2 = idx % 48;
      float acc = conv1_b[obase + o];
      const float* wr = &wl[o * 150];
      for (int c = 0; c < EC_; ++c) {
        const float* ip = &ce[c * 52 + t2];
        acc += wr[c * 3 + 0] * ip[0] + wr[c * 3 + 1] * ip[1] + wr[c * 3 + 2] * ip[2];
      }
      out1[((size_t)b2 * C_ + obase + o) * 48 + t2] = fmaxf(acc, 0.0f);
    }
    flag_signal(&flags[F_C1]);
    return;
  }

  // ================================================================ conv2 (128 blocks)
  else if (bid < RB_C3) {
    flag_wait(&flags[F_C1], NB_C1, 4);
    const int q = bid - RB_C2;
    const int b2 = q & 31, ot = q >> 5;
    float* il = sm.c2.il;
    float* wl = sm.c2.wl;
    const int tid = threadIdx.x;
    for (int idx = tid; idx < C_ * 48; idx += 256) il[idx] = out1[(size_t)b2 * C_ * 48 + idx];
    int obase = ot * 25;
    for (int idx = tid; idx < 25 * 400; idx += 256) wl[idx] = conv2_w[obase * 400 + idx];
    __syncthreads();
    for (int idx = tid; idx < 25 * 45; idx += 256) {
      int o = idx / 45, t2 = idx % 45;
      float acc = conv2_b[obase + o];
      const float* wr = &wl[o * 400];
      for (int c = 0; c < C_; ++c) {
        const float* ip = &il[c * 48 + t2];
        acc += wr[c * 4 + 0] * ip[0] + wr[c * 4 + 1] * ip[1] +
               wr[c * 4 + 2] * ip[2] + wr[c * 4 + 3] * ip[3];
      }
      out2[((size_t)b2 * C_ + obase + o) * 45 + t2] = fmaxf(acc, 0.0f);
    }
    flag_signal(&flags[F_C2]);
    return;
  }

  // ================================================================ conv3 + maxpool (160 blocks)
  else if (bid < RB_PW) {
    flag_wait(&flags[F_C2], NB_C2, 4);
    const int q = bid - RB_C3;
    const int b2 = q % 32, ot = q / 32;
    float* il = sm.c3.il;
    float* wl = sm.c3.wl;
    float* o3 = sm.c3.o3;
    const int tid = threadIdx.x;
    for (int idx = tid; idx < C_ * 45; idx += 256) il[idx] = out2[(size_t)b2 * C_ * 45 + idx];
    int obase = ot * 20;
    for (int idx = tid; idx < 20 * 500; idx += 256) wl[idx] = conv3_w[obase * 500 + idx];
    __syncthreads();
    for (int idx = tid; idx < 20 * 41; idx += 256) {
      int o = idx / 41, t2 = idx % 41;
      float acc = conv3_b[obase + o];
      const float* wr = &wl[o * 500];
      for (int c = 0; c < C_; ++c) {
        const float* ip = &il[c * 45 + t2];
        acc += wr[c * 5 + 0] * ip[0] + wr[c * 5 + 1] * ip[1] + wr[c * 5 + 2] * ip[2] +
               wr[c * 5 + 3] * ip[3] + wr[c * 5 + 4] * ip[4];
      }
      o3[o * 44 + t2] = fmaxf(acc, 0.0f);
    }
    __syncthreads();
    if (tid < 20) {
      float m = o3[tid * 44];
      for (int t2 = 1; t2 < 41; ++t2) m = fmaxf(m, o3[tid * 44 + t2]);
      pooled[b2 * C_ + obase + tid] = m;
    }
    flag_signal(&flags[F_C3]);
    return;
  }

  // ================================================================ prep_w (64 blocks, strided)
  else if (bid < RB_PB) {
    const int q = bid - RB_PW;
    const int total = 2 * G4_ * KP_;
    for (int idx = q * 256 + (int)threadIdx.x; idx < total; idx += NB_PW * 256) {
      int d = idx / (G4_ * KP_);
      int rem = idx % (G4_ * KP_);
      int j = rem / KP_, k2 = rem % KP_;
      const float* w2 = d ? w_ih_b : w_ih_f;
      float v0 = 0.f, v1 = 0.f;
      if (k2 < 200) { v0 = w2[(size_t)j * DHID_ + 2 * k2]; v1 = w2[(size_t)j * DHID_ + 2 * k2 + 1]; }
      unsigned p0 = pack_split(v0), p1 = pack_split(v1);
      apH[idx] = (p0 & 0xFFFFu) | (p1 << 16);
      apL[idx] = (p0 >> 16) | (p1 & 0xFFFF0000u);
    }
    flag_signal(&flags[F_PW]);
    return;
  }

  // ================================================================ prep_b (512 blocks × 8 rows)
  else if (bid < RB_GEMM) {
    flag_wait(&flags[F_C3], NB_C3, 8);
    const int q = bid - RB_PB;
    const int tid = threadIdx.x;
    if (tid < KP_) {
      int k2 = tid;
      for (int rr = 0; rr < 8; ++rr) {
        int r = q * 8 + rr;
        int t2 = r >> 5, b2 = r & 31;
        float v0 = 0.f, v1 = 0.f;
        if (k2 < 150) {
          const float* e2 = word_emb + (size_t)x[b2 * S_ + t2] * E_;
          v0 = e2[2 * k2]; v1 = e2[2 * k2 + 1];
        } else if (k2 < 200) {
          v0 = pooled[b2 * C_ + 2 * k2 - 300];
          v1 = pooled[b2 * C_ + 2 * k2 - 299];
        }
        unsigned p0 = pack_split(v0), p1 = pack_split(v1);
        bpH[(size_t)r * KP_ + k2] = (p0 & 0xFFFFu) | (p1 << 16);
        bpL[(size_t)r * KP_ + k2] = (p0 >> 16) | (p1 & 0xFFFF0000u);
      }
    }
    flag_signal(&flags[F_PB]);
    return;
  }

  // ================================================================ input GEMM (512 blocks)
  else if (bid < RB_FC) {
    flag_wait(&flags[F_PW], NB_PW, 16);
    flag_wait(&flags[F_PB], NB_PB, 16);
    const int q = bid - RB_GEMM;
    // d fastest; backward direction consumes t descending -> give it rt descending
    const int d = q & 1;
    const int jt = (q >> 1) & 7;
    const int rtb = q >> 4;
    const int rt = d ? (31 - rtb) : rtb;
    const int j0 = jt * 128, r0 = rt * 128;
    const int tid = threadIdx.x;
    const int w = tid >> 6, l = tid & 63;
    const int lx = l & 15, lq = l >> 4;

    unsigned* aH = sm.gemm.aH;
    unsigned* aL = sm.gemm.aL;
    unsigned* bH = sm.gemm.bH;
    unsigned* bL = sm.gemm.bL;

    f32x4 acch[2][8], accl[2][8];
#pragma unroll
    for (int mt = 0; mt < 2; ++mt)
#pragma unroll
      for (int nt = 0; nt < 8; ++nt) {
        f32x4 z = {0.f, 0.f, 0.f, 0.f};
        acch[mt][nt] = z; accl[mt][nt] = z;
      }

    const int jr = tid >> 1, hh = tid & 1;
    const int q_st = jr >> 4, lane_lo = jr & 15;
    const unsigned* arH = apH + ((size_t)(d * G4_ + j0 + jr)) * KP_ + hh * 8;
    const unsigned* arL = apL + ((size_t)(d * G4_ + j0 + jr)) * KP_ + hh * 8;
    const unsigned* brH = bpH + ((size_t)(r0 + jr)) * KP_ + hh * 8;
    const unsigned* brL = bpL + ((size_t)(r0 + jr)) * KP_ + hh * 8;
    const int w0 = (q_st * 64 + lane_lo + 32 * hh) * 4;
    const int w1 = (q_st * 64 + lane_lo + 32 * hh + 16) * 4;

    for (int Kt = 0; Kt < 13; ++Kt) {
      uint4 a0 = *(const uint4*)(arH + Kt * 16);
      uint4 a1 = *(const uint4*)(arH + Kt * 16 + 4);
      uint4 c0v = *(const uint4*)(arL + Kt * 16);
      uint4 c1v = *(const uint4*)(arL + Kt * 16 + 4);
      uint4 e0 = *(const uint4*)(brH + Kt * 16);
      uint4 e1 = *(const uint4*)(brH + Kt * 16 + 4);
      uint4 f0 = *(const uint4*)(brL + Kt * 16);
      uint4 f1 = *(const uint4*)(brL + Kt * 16 + 4);
      *(uint4*)&aH[w0] = a0; *(uint4*)&aH[w1] = a1;
      *(uint4*)&aL[w0] = c0v; *(uint4*)&aL[w1] = c1v;
      *(uint4*)&bH[w0] = e0; *(uint4*)&bH[w1] = e1;
      *(uint4*)&bL[w0] = f0; *(uint4*)&bL[w1] = f1;
      __syncthreads();

      union u4h { uint4 u; half8 h; };
      u4h AH0, AH1, AL0, AL1;
      AH0.u = *(const uint4*)&aH[((2 * w + 0) * 64 + l) * 4];
      AH1.u = *(const uint4*)&aH[((2 * w + 1) * 64 + l) * 4];
      AL0.u = *(const uint4*)&aL[((2 * w + 0) * 64 + l) * 4];
      AL1.u = *(const uint4*)&aL[((2 * w + 1) * 64 + l) * 4];
#pragma unroll
      for (int nt = 0; nt < 8; ++nt) {
        u4h BHn, BLn;
        BHn.u = *(const uint4*)&bH[(nt * 64 + l) * 4];
        BLn.u = *(const uint4*)&bL[(nt * 64 + l) * 4];
        acch[0][nt] = __builtin_amdgcn_mfma_f32_16x16x32_f16(AH0.h, BHn.h, acch[0][nt], 0, 0, 0);
        accl[0][nt] = __builtin_amdgcn_mfma_f32_16x16x32_f16(AH0.h, BLn.h, accl[0][nt], 0, 0, 0);
        accl[0][nt] = __builtin_amdgcn_mfma_f32_16x16x32_f16(AL0.h, BHn.h, accl[0][nt], 0, 0, 0);
        acch[1][nt] = __builtin_amdgcn_mfma_f32_16x16x32_f16(AH1.h, BHn.h, acch[1][nt], 0, 0, 0);
        accl[1][nt] = __builtin_amdgcn_mfma_f32_16x16x32_f16(AH1.h, BLn.h, accl[1][nt], 0, 0, 0);
        accl[1][nt] = __builtin_amdgcn_mfma_f32_16x16x32_f16(AL1.h, BHn.h, accl[1][nt], 0, 0, 0);
      }
      __syncthreads();
    }

    const float* bias = d ? b_b : b_f;
    const float inv2048 = 1.0f / 2048.0f;
#pragma unroll
    for (int mt = 0; mt < 2; ++mt) {
#pragma unroll
      for (int nt = 0; nt < 8; ++nt) {
        int rr = r0 + nt * 16 + lx;
        int tt = rr >> 5, bb2 = rr & 31;
        unsigned* dst = (unsigned*)gi + ((size_t)(d * S_ + tt) * G4_) * B_ + bb2;
#pragma unroll
        for (int r4 = 0; r4 < 4; ++r4) {
          int j = j0 + (2 * w + mt) * 16 + lq * 4 + r4;
          float vv = acch[mt][nt][r4] + accl[mt][nt][r4] * inv2048 + bias[j];
          __hip_atomic_store(&dst[(size_t)j * B_], __builtin_bit_cast(unsigned, vv),
                             __ATOMIC_RELAXED, __HIP_MEMORY_SCOPE_AGENT);
        }
      }
    }
    return;
  }

  // ================================================================ FC -> emissions (128 blocks)
  else if (bid < RB_SMV) {
    const int s = bid - RB_FC;
    const int tid = threadIdx.x;
    float* wT = sm.fc.wT;
    float* psum = sm.fc.psum;
    for (int i = tid; i < L_ * 512; i += 256) {
      int l2 = i / 512, k = i % 512;
      wT[k * 18 + l2] = fc_w[i];
    }
    const float* hf = hbuf + (size_t)(s + 1) * (H_ * B_);
    const float* hbk = hbuf + (size_t)(S_ + 1 + (S_ - s)) * (H_ * B_);
    const unsigned* hfu = (const unsigned*)hf;
    const unsigned* hbku = (const unsigned*)hbk;
    // cheap proxy poll (1 broadcast word per direction) while the lstm runs
    for (;;) {
      unsigned a = __hip_atomic_load(&hfu[0], __ATOMIC_RELAXED, __HIP_MEMORY_SCOPE_AGENT);
      unsigned c = __hip_atomic_load(&hbku[0], __ATOMIC_RELAXED, __HIP_MEMORY_SCOPE_AGENT);
      if (a != SENTF_ && c != SENTF_) break;
      __builtin_amdgcn_s_sleep(32);
    }
    const int b2 = tid & 31, kq = tid >> 5;
    const unsigned* basep = (kq < 4) ? hfu : hbku;
    const int koff = (kq < 4) ? kq * 64 : kq * 64 - 256;
    unsigned hraw[64];
    for (;;) {
      bool pend = false;
#pragma unroll
      for (int i = 0; i < 64; ++i)
        hraw[i] = __hip_atomic_load(&basep[(size_t)(koff + i) * 32 + b2],
                                    __ATOMIC_RELAXED, __HIP_MEMORY_SCOPE_AGENT);
#pragma unroll
      for (int i = 0; i < 64; ++i) pend |= (hraw[i] == SENTF_);
      if (!pend) break;
      __builtin_amdgcn_s_sleep(8);
    }
    __syncthreads();
    float acc[L_];
#pragma unroll
    for (int l2 = 0; l2 < L_; ++l2) acc[l2] = 0.f;
#pragma unroll
    for (int i = 0; i < 64; ++i) {
      int k = kq * 64 + i;
      float hv = __builtin_bit_cast(float, hraw[i]);
      const float* wr = &wT[k * 18];
#pragma unroll
      for (int l2 = 0; l2 < L_; ++l2) acc[l2] = fmaf(hv, wr[l2], acc[l2]);
    }
#pragma unroll
    for (int l2 = 0; l2 < L_; ++l2) psum[tid * 18 + l2] = acc[l2];
    __syncthreads();
    for (int idx = tid; idx < B_ * L_; idx += 256) {
      int bb2 = idx & 31, l2 = idx >> 5;
      float sum = fc_b[l2];
      for (int q2 = 0; q2 < 8; ++q2) sum += psum[(q2 * 32 + bb2) * 18 + l2];
      __hip_atomic_store((unsigned*)&em[((size_t)bb2 * S_ + s) * L_ + l2],
                         __builtin_bit_cast(unsigned, sum),
                         __ATOMIC_RELAXED, __HIP_MEMORY_SCOPE_AGENT);
    }
    return;
  }

  // ================================================================ softmax + viterbi (32 blocks)
  else {
    const int bb = bid - RB_SMV;
    const int tid = threadIdx.x;
    float* e = sm.smv.e;
    float* tr = sm.smv.tr;
    auto sc = sm.smv.sc;
    int* hist = sm.smv.hist;
    int* tags = sm.smv.tags;

    int ei[9];
#pragma unroll
    for (int j = 0; j < 9; ++j) { int i = tid + j * 256; ei[j] = (i < S_ * L_) ? i : tid; }
    const unsigned* emu = (const unsigned*)em + (size_t)bb * S_ * L_;
    unsigned ev[9];
    for (;;) {
      bool pend = false;
#pragma unroll
      for (int j = 0; j < 9; ++j)
        ev[j] = __hip_atomic_load(&emu[ei[j]], __ATOMIC_RELAXED, __HIP_MEMORY_SCOPE_AGENT);
#pragma unroll
      for (int j = 0; j < 9; ++j) pend |= (ev[j] == SENTF_);
      if (!pend) break;
      __builtin_amdgcn_s_sleep(127);
    }
#pragma unroll
    for (int j = 0; j < 9; ++j) e[ei[j]] = __builtin_bit_cast(float, ev[j]);
    for (int i = tid; i < L_ * L_; i += 256) tr[i] = trans[i];
    __syncthreads();
    if (tid < L_) {
      int l2 = tid;
      float m = -INFINITY;
      for (int s2 = 0; s2 < S_; ++s2) m = fmaxf(m, e[s2 * L_ + l2]);
      float sum2 = 0.f;
      for (int s2 = 0; s2 < S_; ++s2) {
        float ex = expf(e[s2 * L_ + l2] - m);
        e[s2 * L_ + l2] = ex;
        sum2 += ex;
      }
      for (int s2 = 0; s2 < S_; ++s2) e[s2 * L_ + l2] = e[s2 * L_ + l2] / sum2;
    }
    __syncthreads();
    if (tid < L_) sc[0][tid] = start_t[tid] + e[tid];
    __syncthreads();
    int cbuf = 0;
    for (int t2 = 1; t2 < S_; ++t2) {
      if (tid < L_) {
        int j2 = tid;
        float evv = e[t2 * L_ + j2];
        float best = -INFINITY;
        int arg = 0;
        for (int i = 0; i < L_; ++i) {
          float v = (sc[cbuf][i] + tr[i * L_ + j2]) + evv;
          if (v > best) { best = v; arg = i; }  // strict >: first occurrence like np.argmax
        }
        int maskt = (x[bb * S_ + t2] != 0);
        sc[cbuf ^ 1][j2] = maskt ? best : sc[cbuf][j2];
        hist[(t2 - 1) * L_ + j2] = arg;
      }
      __syncthreads();
      cbuf ^= 1;
    }
    if (tid == 0) {
      float best = -INFINITY;
      int last = 0;
      for (int j2 = 0; j2 < L_; ++j2) {
        float v = sc[cbuf][j2] + end_t[j2];
        if (v > best) { best = v; last = j2; }
      }
      int cur = last;
      tags[S_ - 1] = cur;
      for (int p = S_ - 2; p >= 0; --p) {
        if (x[bb * S_ + p + 1] != 0) cur = hist[p * L_ + cur];
        tags[p] = cur;
      }
    }
    __syncthreads();
    for (int s2 = tid; s2 < S_; s2 += 256) out[bb * S_ + s2] = tags[s2];
    return;
  }
}

// ---------------------------------------------------------------- launch
extern "C" void kernel_launch(void* const* d_in, const int* in_sizes, int n_in,
                              void* d_out, int out_size, void* d_ws, size_t ws_size,
                              hipStream_t stream) {
  const int* x        = (const int*)d_in[0];
  const int* x_char   = (const int*)d_in[1];
  const float* word_emb = (const float*)d_in[2];
  const float* char_emb = (const float*)d_in[3];
  const float* conv1_w = (const float*)d_in[4];
  const float* conv1_b = (const float*)d_in[5];
  const float* conv2_w = (const float*)d_in[6];
  const float* conv2_b = (const float*)d_in[7];
  const float* conv3_w = (const float*)d_in[8];
  const float* conv3_b = (const float*)d_in[9];
  const float* w_ih_f = (const float*)d_in[10];
  const float* w_hh_f = (const float*)d_in[11];
  const float* b_f    = (const float*)d_in[12];
  const float* w_ih_b = (const float*)d_in[13];
  const float* w_hh_b = (const float*)d_in[14];
  const float* b_b    = (const float*)d_in[15];
  const float* h0     = (const float*)d_in[16];
  const float* c0     = (const float*)d_in[17];
  const float* fc_w   = (const float*)d_in[18];
  const float* fc_b   = (const float*)d_in[19];
  const float* start_t = (const float*)d_in[20];
  const float* trans  = (const float*)d_in[21];
  const float* end_t  = (const float*)d_in[22];
  int* out = (int*)d_out;

  char* ws = (char*)d_ws;
  auto alloc = [&](size_t bytes) -> char* {
    char* p = ws;
    ws += (bytes + 1023) & ~(size_t)1023;
    return p;
  };
  float* pooled  = (float*)alloc(sizeof(float) * B_ * C_);
  float* gi      = (float*)alloc(sizeof(float) * 2 * S_ * G4_ * B_);
  float* hbuf    = (float*)alloc(sizeof(float) * 2 * (S_ + 1) * H_ * B_);
  unsigned* hfrag = (unsigned*)alloc(sizeof(unsigned) * 2 * (S_ + 1) * SLAB_);
  unsigned* apH  = (unsigned*)alloc(sizeof(unsigned) * 2 * G4_ * KP_);
  unsigned* apL  = (unsigned*)alloc(sizeof(unsigned) * 2 * G4_ * KP_);
  unsigned* bpH  = (unsigned*)alloc(sizeof(unsigned) * 4096 * KP_);
  unsigned* bpL  = (unsigned*)alloc(sizeof(unsigned) * 4096 * KP_);
  float* out1    = (float*)alloc(sizeof(float) * B_ * C_ * 48);
  float* out2    = (float*)alloc(sizeof(float) * B_ * C_ * 45);
  float* em      = (float*)alloc(sizeof(float) * B_ * S_ * L_);
  int* flags     = (int*)alloc(sizeof(int) * 16);

  k_fill<<<2048, 256, 0, stream>>>(h0, hfrag, (unsigned*)hbuf, (unsigned*)gi,
                                   (unsigned*)em, flags);
  k_mega<<<NBLK_MEGA, 256, 0, stream>>>(
      x, x_char, word_emb, char_emb,
      conv1_w, conv1_b, conv2_w, conv2_b, conv3_w, conv3_b,
      w_ih_f, w_ih_b, w_hh_f, w_hh_b, b_f, b_b, c0, fc_w, fc_b,
      start_t, trans, end_t,
      pooled, gi, hbuf, hfrag, apH, apL, bpH, bpL, out1, out2, em, flags, out);
}

// Round 3
// 1088.357 us; speedup vs baseline: 1.5439x; 1.0167x over previous
//
#include <hip/hip_runtime.h>
#include <cmath>

#define B_   32
#define S_   128
#define E_   300
#define C_   100
#define EC_  50
#define LC_  50
#define H_   256
#define G4_  1024   // 4*H
#define L_   17
#define DHID_ 400   // E + C
#define SLAB_ 8192  // u32 per (d,t) frag slab: [Nt(2)][Kt(8)][lane(64)][hi m0..3 | lo m4..7]
#define SENT2_ 0x7E007E00u  // fp16-NaN in both halves: legit packed pair never matches
#define SENTF_ 0x7FC0DEADu  // fp32 qNaN sentinel: legit finite result never matches
#define KP_   208   // k-pairs per row in packed GEMM operands (416 k, zero-padded from 400)

// ---- mega-kernel role layout (dispatch order = dependency-safe order) ----
#define RB_LSTM 0
#define NB_LSTM 16
#define RB_C1   16
#define NB_C1   64
#define RB_C2   80
#define NB_C2   128
#define RB_C3   208
#define NB_C3   160
#define RB_PW   368
#define NB_PW   64
#define RB_PB   432
#define NB_PB   128
#define RB_GEMM 560
#define NB_GEMM 512
#define RB_FC   1072
#define NB_FC   128
#define RB_SMV  1200
#define NB_SMV  32
#define NBLK_MEGA 1232

#define F_C1 0
#define F_C2 1
#define F_C3 2
#define F_PW 3
#define F_PB 4
#define F_PBE 5
#define FG_BASE 8   // gdone[d][rt]: 64 counters, target 8 (jt blocks) each

typedef _Float16 half8 __attribute__((ext_vector_type(8)));
typedef float f32x4 __attribute__((ext_vector_type(4)));
typedef unsigned long long ull;
struct __align__(16) U2 { ull x, y; };

// split fp32 -> (hi fp16, lo fp16 scaled by 2048), packed u32 (hi in low16).
__device__ __forceinline__ unsigned pack_split(float v) {
  _Float16 hi = (fabsf(v) >= 6.104e-5f) ? (_Float16)v : (_Float16)0.0f;
  float hif = (float)hi;
  _Float16 lo = (_Float16)((v - hif) * 2048.0f);
  return (unsigned)__builtin_bit_cast(unsigned short, hi)
       | ((unsigned)__builtin_bit_cast(unsigned short, lo) << 16);
}

__device__ __forceinline__ void flag_signal(int* f) {
  __syncthreads();   // all threads' stores drained (waitcnt before s_barrier)
  if (threadIdx.x == 0)
    __hip_atomic_fetch_add(f, 1, __ATOMIC_RELEASE, __HIP_MEMORY_SCOPE_AGENT);
}
__device__ __forceinline__ void flag_wait(const int* f, int target, int slp) {
  while (__hip_atomic_load(f, __ATOMIC_ACQUIRE, __HIP_MEMORY_SCOPE_AGENT) < target) {
    switch (slp) {
      case 4:  __builtin_amdgcn_s_sleep(4);  break;
      case 8:  __builtin_amdgcn_s_sleep(8);  break;
      default: __builtin_amdgcn_s_sleep(16); break;
    }
  }
}

// LDS union: one static allocation, role-dependent view. Max member = conv3 (61.5 KB).
union SMem {
  struct { unsigned aH[2048], aL[2048], bH[2048], bL[2048]; } gemm;                     // 32 KB
  struct { ull slh[2048], sll[2048]; float gl[4 * 32 * 33]; unsigned ps[2 * 576]; } lstm; // 54.2 KB
  struct { float ce[EC_ * 52]; float wl[50 * 150]; int ids[LC_]; } c1;
  struct { float il[C_ * 48]; float wl[25 * 400]; } c2;                                  // 59.2 KB
  struct { float il[C_ * 45]; float wl[20 * 500]; float o3[20 * 44]; } c3;               // 61.5 KB
  struct { float wT[512 * 18]; float psum[256 * 18]; } fc;                               // 55.3 KB
  struct { float e[S_ * L_]; float tr[L_ * L_]; float sc[2][L_];
           int hist[(S_ - 1) * L_]; int tags[S_]; } smv;
};

// ---------------------------------------------------------------- fill: hfrag init + hbuf/em sentinels + flags
// gi is NO LONGER sentinel-filled: LSTM is flag-gated on gdone (removes the 33.5 MB fill
// AND the full-rate 32-load LLC spin the LSTM ran during the whole prefix in R2).
__global__ void k_fill(const float* __restrict__ h0, unsigned* __restrict__ hfrag,
                       unsigned* __restrict__ hbufU, unsigned* __restrict__ emU,
                       int* __restrict__ flags) {
  const int g0 = blockIdx.x * 256 + threadIdx.x;
  const int nth = gridDim.x * 256;
  const int htot = 2 * (S_ + 1) * SLAB_;
  for (int idx = g0; idx < htot; idx += nth) {
    int sd = idx / SLAB_;
    int within = idx % SLAB_;
    int t = sd % (S_ + 1), d = sd / (S_ + 1);
    if (t != 0) { hfrag[idx] = SENT2_; continue; }
    int m8 = within & 7;
    int lane = (within >> 3) & 63;
    int q = within >> 9;
    int Kt = q & 7, Nt = q >> 3;
    int m = m8 & 3, isLo = m8 >> 2;
    int k0 = Kt * 32 + (lane >> 4) * 8 + 2 * m;
    int b = Nt * 16 + (lane & 15);
    unsigned p0 = pack_split(h0[((size_t)d * B_ + b) * H_ + k0]);
    unsigned p1 = pack_split(h0[((size_t)d * B_ + b) * H_ + k0 + 1]);
    unsigned hiw = (p0 & 0xFFFFu) | (p1 << 16);
    unsigned low = (p0 >> 16) | (p1 & 0xFFFF0000u);
    hfrag[idx] = isLo ? low : hiw;
  }
  const int hbtot = 2 * (S_ + 1) * H_ * B_;
  for (int idx = g0; idx < hbtot; idx += nth) hbufU[idx] = SENTF_;
  const int etot = B_ * S_ * L_;
  for (int idx = g0; idx < etot; idx += nth) emU[idx] = SENTF_;
  if (g0 < 128) flags[g0] = 0;
}

// ---------------------------------------------------------------- mega: all stages, one launch
__global__ __launch_bounds__(256) void k_mega(
    const int* __restrict__ x, const int* __restrict__ x_char,
    const float* __restrict__ word_emb, const float* __restrict__ char_emb,
    const float* __restrict__ conv1_w, const float* __restrict__ conv1_b,
    const float* __restrict__ conv2_w, const float* __restrict__ conv2_b,
    const float* __restrict__ conv3_w, const float* __restrict__ conv3_b,
    const float* __restrict__ w_ih_f, const float* __restrict__ w_ih_b,
    const float* __restrict__ w_hh_f, const float* __restrict__ w_hh_b,
    const float* __restrict__ b_f, const float* __restrict__ b_b,
    const float* __restrict__ c0,
    const float* __restrict__ fc_w, const float* __restrict__ fc_b,
    const float* __restrict__ start_t, const float* __restrict__ trans,
    const float* __restrict__ end_t,
    float* __restrict__ pooled, float* __restrict__ gi, float* __restrict__ hbuf,
    unsigned* __restrict__ hfrag,
    unsigned* __restrict__ apH, unsigned* __restrict__ apL,
    unsigned* __restrict__ bpH, unsigned* __restrict__ bpL,
    float* __restrict__ out1, float* __restrict__ out2,
    float* __restrict__ em, int* __restrict__ flags, int* __restrict__ out) {
  const int bid = blockIdx.x;
  __shared__ SMem sm;

  // ================================================================ LSTM (bids 0..15)
  if (bid < RB_C1) {
    __builtin_amdgcn_s_setprio(2);  // recurrence is the critical path; win CU arbitration
    const int iblk = bid & 7;
    const int d = bid >> 3;
    const float* whh = d ? w_hh_b : w_hh_f;
    const int tid = threadIdx.x;
    const int w = tid >> 6;          // wave index = gate (i,f,g,o)
    const int l = tid & 63;
    const int lx = l & 15, lq = l >> 4;
    const int u0 = iblk * 32;

    ull* slh = sm.lstm.slh;
    ull* sll = sm.lstm.sll;
    float* glb = sm.lstm.gl;
    unsigned* ps = sm.lstm.ps;

    half8 whi[2][8], wlo[2][8];
#pragma unroll
    for (int Mt = 0; Mt < 2; ++Mt) {
#pragma unroll
      for (int Kt = 0; Kt < 8; ++Kt) {
        int row = w * H_ + u0 + Mt * 16 + lx;
        int kk0 = Kt * 32 + lq * 8;
        const float* src = whh + (size_t)row * H_ + kk0;
        float4 f0 = *(const float4*)src;
        float4 f1 = *(const float4*)(src + 4);
        float wv[8] = {f0.x, f0.y, f0.z, f0.w, f1.x, f1.y, f1.z, f1.w};
        union { unsigned short s2[8]; half8 h; } HI, LO;
#pragma unroll
        for (int j = 0; j < 8; ++j) {
          float v = wv[j];
          _Float16 hi = (fabsf(v) >= 6.104e-5f) ? (_Float16)v : (_Float16)0.0f;
          float hif = (float)hi;
          _Float16 lo = (_Float16)((v - hif) * 2048.0f);
          HI.s2[j] = __builtin_bit_cast(unsigned short, hi);
          LO.s2[j] = __builtin_bit_cast(unsigned short, lo);
        }
        whi[Mt][Kt] = HI.h;
        wlo[Mt][Kt] = LO.h;
      }
    }

    const int bc = tid & 31, cw = tid >> 5;
    float creg[4];
#pragma unroll
    for (int cu = 0; cu < 4; ++cu)
      creg[cu] = c0[((size_t)d * B_ + bc) * H_ + u0 + cu * 8 + cw];

    const int pNt = bc >> 4;
    const int pm = cw >> 1;
    const bool phi = (cw & 1) == 0;
    const int plane = bc & 15;
    const float inv2048 = 1.0f / 2048.0f;

    int rt_have = -1;
    for (int t = 0; t < S_; ++t) {
      int torig = d ? (S_ - 1 - t) : t;

      // gate on GEMM completion for this 4-step r-range; only re-polls when rt changes.
      // gi lines are only ever written via write-through agent atomics and never cached
      // on this CU before first read -> plain loads after the gate observe LLC-current data.
      int rt = torig >> 2;
      if (rt != rt_have) {
        if (tid == 0) {
          const int* gf = &flags[FG_BASE + d * 32 + rt];
          while (__hip_atomic_load(gf, __ATOMIC_ACQUIRE, __HIP_MEMORY_SCOPE_AGENT) < 8)
            __builtin_amdgcn_s_sleep(2);
        }
        __syncthreads();
        rt_have = rt;
      }

      // plain gi loads (round-0 pattern) — in flight during the hfrag spin below
      f32x4 acch[2][2], accl[2][2];
      {
        const float* gbase = gi + ((size_t)(d * S_ + torig) * G4_) * B_;
#pragma unroll
        for (int Mt = 0; Mt < 2; ++Mt)
#pragma unroll
          for (int Nt = 0; Nt < 2; ++Nt) {
            f32x4 v;
#pragma unroll
            for (int r = 0; r < 4; ++r) {
              int j = w * H_ + u0 + Mt * 16 + lq * 4 + r;
              v[r] = gbase[(size_t)j * B_ + Nt * 16 + lx];
            }
            acch[Mt][Nt] = v;
            f32x4 z = {0.f, 0.f, 0.f, 0.f};
            accl[Mt][Nt] = z;
          }
      }

      // spin on previous-step h fragments (unchanged protocol)
      const ull* hp = (const ull*)(hfrag + (size_t)(d * (S_ + 1) + t) * SLAB_);
      ull pv[4][4];
#pragma unroll
      for (int c = 0; c < 4; ++c) {
        size_t base = ((size_t)(w * 4 + c) * 64 + l) * 4;
#pragma unroll
        for (int j = 0; j < 4; ++j)
          pv[c][j] = __hip_atomic_load(&hp[base + j], __ATOMIC_RELAXED,
                                       __HIP_MEMORY_SCOPE_AGENT);
      }
      for (;;) {
        bool pending = false;
#pragma unroll
        for (int c = 0; c < 4; ++c)
#pragma unroll
          for (int j = 0; j < 4; ++j)
            pending |= ((unsigned)pv[c][j] == SENT2_) |
                       ((unsigned)(pv[c][j] >> 32) == SENT2_);
        if (!pending) break;
#pragma unroll
        for (int c = 0; c < 4; ++c) {
          size_t base = ((size_t)(w * 4 + c) * 64 + l) * 4;
#pragma unroll
          for (int j = 0; j < 4; ++j)
            pv[c][j] = __hip_atomic_load(&hp[base + j], __ATOMIC_RELAXED,
                                         __HIP_MEMORY_SCOPE_AGENT);
        }
      }

#pragma unroll
      for (int c = 0; c < 4; ++c) {
        int idx = ((w * 4 + c) * 64 + l) * 2;
        U2 vh; vh.x = pv[c][0]; vh.y = pv[c][1];
        U2 vl; vl.x = pv[c][2]; vl.y = pv[c][3];
        *(U2*)&slh[idx] = vh;
        *(U2*)&sll[idx] = vl;
      }
      __syncthreads();

#pragma unroll
      for (int Kt = 0; Kt < 8; ++Kt) {
        half8 Bhi[2], Blo[2];
#pragma unroll
        for (int Nt = 0; Nt < 2; ++Nt) {
          int idx = ((Nt * 8 + Kt) * 64 + l) * 2;
          union { U2 u; half8 h; } UH, UL;
          UH.u = *(const U2*)&slh[idx];
          UL.u = *(const U2*)&sll[idx];
          Bhi[Nt] = UH.h;
          Blo[Nt] = UL.h;
        }
#pragma unroll
        for (int Mt = 0; Mt < 2; ++Mt)
#pragma unroll
          for (int Nt = 0; Nt < 2; ++Nt) {
            acch[Mt][Nt] = __builtin_amdgcn_mfma_f32_16x16x32_f16(
                whi[Mt][Kt], Bhi[Nt], acch[Mt][Nt], 0, 0, 0);
            accl[Mt][Nt] = __builtin_amdgcn_mfma_f32_16x16x32_f16(
                whi[Mt][Kt], Blo[Nt], accl[Mt][Nt], 0, 0, 0);
            accl[Mt][Nt] = __builtin_amdgcn_mfma_f32_16x16x32_f16(
                wlo[Mt][Kt], Bhi[Nt], accl[Mt][Nt], 0, 0, 0);
          }
      }

#pragma unroll
      for (int Mt = 0; Mt < 2; ++Mt)
#pragma unroll
        for (int Nt = 0; Nt < 2; ++Nt)
#pragma unroll
          for (int r = 0; r < 4; ++r) {
            int ul = Mt * 16 + lq * 4 + r;
            glb[(w * 32 + ul) * 33 + Nt * 16 + lx] =
                acch[Mt][Nt][r] + accl[Mt][Nt][r] * inv2048;
          }
      __syncthreads();

      float hreg[4];
#pragma unroll
      for (int cu = 0; cu < 4; ++cu) {
        int u = cu * 8 + cw;
        float g_i = glb[(0 * 32 + u) * 33 + bc];
        float g_f = glb[(1 * 32 + u) * 33 + bc];
        float g_g = glb[(2 * 32 + u) * 33 + bc];
        float g_o = glb[(3 * 32 + u) * 33 + bc];
        float si = 1.f / (1.f + __expf(-g_i));
        float sf = 1.f / (1.f + __expf(-g_f));
        float so = 1.f / (1.f + __expf(-g_o));
        float tg = 1.f - 2.f / (__expf(2.f * g_g) + 1.f);
        float cn = sf * creg[cu] + si * tg;
        float tc = 1.f - 2.f / (__expf(2.f * cn) + 1.f);
        float hn = so * tc;
        creg[cu] = cn;
        hreg[cu] = hn;
        unsigned me = pack_split(hn);
        unsigned pa = (unsigned)__shfl_xor((int)me, 32, 64);
        unsigned je = (cw & 1) ? pa : me;
        unsigned jo = (cw & 1) ? me : pa;
        unsigned hiw = (je & 0xFFFFu) | (jo << 16);
        unsigned low = (je >> 16) | (jo & 0xFFFF0000u);
        int lane2 = (cu << 4) | plane;
        int m8 = phi ? pm : (4 + pm);
        ps[pNt * 576 + lane2 * 9 + m8] = phi ? hiw : low;
      }
      __syncthreads();

      {
        ull* slab64 = (ull*)(hfrag + (size_t)(d * (S_ + 1) + t + 1) * SLAB_);
#pragma unroll
        for (int hh2 = 0; hh2 < 2; ++hh2) {
          int r = tid;
          int Nt = hh2;
          int lane2 = r >> 2, m2 = r & 3;
          unsigned a = ps[Nt * 576 + lane2 * 9 + 2 * m2];
          unsigned b2 = ps[Nt * 576 + lane2 * 9 + 2 * m2 + 1];
          ull v = (ull)a | ((ull)b2 << 32);
          __hip_atomic_store(&slab64[(size_t)(Nt * 8 + iblk) * 256 + r], v,
                             __ATOMIC_RELAXED, __HIP_MEMORY_SCOPE_AGENT);
        }
        // hbuf published with write-through agent stores (fc sentinel-polls it)
        float* hb = hbuf + (size_t)(d * (S_ + 1) + t + 1) * (H_ * B_) + u0 * B_;
#pragma unroll
        for (int cu = 0; cu < 4; ++cu)
          __hip_atomic_store(&hb[cu * 256 + tid], hreg[cu],
                             __ATOMIC_RELAXED, __HIP_MEMORY_SCOPE_AGENT);
      }
    }
    return;
  }

  // ================================================================ conv1 (64 blocks)
  else if (bid < RB_C2) {
    const int q = bid - RB_C1;
    const int b2 = q & 31, ot = q >> 5;
    float* ce = sm.c1.ce;
    float* wl = sm.c1.wl;
    int* ids = sm.c1.ids;
    const int tid = threadIdx.x;
    if (tid < LC_) ids[tid] = x_char[b2 * LC_ + tid];
    __syncthreads();
    for (int idx = tid; idx < LC_ * EC_; idx += 256) {
      int t2 = idx / EC_, ec = idx % EC_;
      ce[ec * 52 + t2] = char_emb[ids[t2] * EC_ + ec];
    }
    int obase = ot * 50;
    for (int idx = tid; idx < 50 * 150; idx += 256)
      wl[idx] = conv1_w[obase * 150 + idx];
    __syncthreads();
    for (int idx = tid; idx < 50 * 48; idx += 256) {
      int o = idx / 48, t2 = idx % 48;
      float acc = conv1_b[obase + o];
      const float* wr = &wl[o * 150];
      for (int c = 0; c < EC_; ++c) {
        const float* ip = &ce[c * 52 + t2];
        acc += wr[c * 3 + 0] * ip[0] + wr[c * 3 + 1] * ip[1] + wr[c * 3 + 2] * ip[2];
      }
      out1[((size_t)b2 * C_ + obase + o) * 48 + t2] = fmaxf(acc, 0.0f);
    }
    flag_signal(&flags[F_C1]);
    return;
  }

  // ================================================================ conv2 (128 blocks)
  else if (bid < RB_C3) {
    flag_wait(&flags[F_C1], NB_C1, 4);
    const int q = bid - RB_C2;
    const int b2 = q & 31, ot = q >> 5;
    float* il = sm.c2.il;
    float* wl = sm.c2.wl;
    const int tid = threadIdx.x;
    for (int idx = tid; idx < C_ * 48; idx += 256) il[idx] = out1[(size_t)b2 * C_ * 48 + idx];
    int obase = ot * 25;
    for (int idx = tid; idx < 25 * 400; idx += 256) wl[idx] = conv2_w[obase * 400 + idx];
    __syncthreads();
    for (int idx = tid; idx < 25 * 45; idx += 256) {
      int o = idx / 45, t2 = idx % 45;
      float acc = conv2_b[obase + o];
      const float* wr = &wl[o * 400];
      for (int c = 0; c < C_; ++c) {
        const float* ip = &il[c * 48 + t2];
        acc += wr[c * 4 + 0] * ip[0] + wr[c * 4 + 1] * ip[1] +
               wr[c * 4 + 2] * ip[2] + wr[c * 4 + 3] * ip[3];
      }
      out2[((size_t)b2 * C_ + obase + o) * 45 + t2] = fmaxf(acc, 0.0f);
    }
    flag_signal(&flags[F_C2]);
    return;
  }

  // ================================================================ conv3 + maxpool (160 blocks)
  else if (bid < RB_PW) {
    flag_wait(&flags[F_C2], NB_C2, 4);
    const int q = bid - RB_C3;
    const int b2 = q % 32, ot = q / 32;
    float* il = sm.c3.il;
    float* wl = sm.c3.wl;
    float* o3 = sm.c3.o3;
    const int tid = threadIdx.x;
    for (int idx = tid; idx < C_ * 45; idx += 256) il[idx] = out2[(size_t)b2 * C_ * 45 + idx];
    int obase = ot * 20;
    for (int idx = tid; idx < 20 * 500; idx += 256) wl[idx] = conv3_w[obase * 500 + idx];
    __syncthreads();
    for (int idx = tid; idx < 20 * 41; idx += 256) {
      int o = idx / 41, t2 = idx % 41;
      float acc = conv3_b[obase + o];
      const float* wr = &wl[o * 500];
      for (int c = 0; c < C_; ++c) {
        const float* ip = &il[c * 45 + t2];
        acc += wr[c * 5 + 0] * ip[0] + wr[c * 5 + 1] * ip[1] + wr[c * 5 + 2] * ip[2] +
               wr[c * 5 + 3] * ip[3] + wr[c * 5 + 4] * ip[4];
      }
      o3[o * 44 + t2] = fmaxf(acc, 0.0f);
    }
    __syncthreads();
    if (tid < 20) {
      float m = o3[tid * 44];
      for (int t2 = 1; t2 < 41; ++t2) m = fmaxf(m, o3[tid * 44 + t2]);
      pooled[b2 * C_ + obase + tid] = m;
    }
    flag_signal(&flags[F_C3]);
    return;
  }

  // ================================================================ prep_w (64 blocks, strided)
  else if (bid < RB_PB) {
    const int q = bid - RB_PW;
    const int total = 2 * G4_ * KP_;
    for (int idx = q * 256 + (int)threadIdx.x; idx < total; idx += NB_PW * 256) {
      int d = idx / (G4_ * KP_);
      int rem = idx % (G4_ * KP_);
      int j = rem / KP_, k2 = rem % KP_;
      const float* w2 = d ? w_ih_b : w_ih_f;
      float v0 = 0.f, v1 = 0.f;
      if (k2 < 200) { v0 = w2[(size_t)j * DHID_ + 2 * k2]; v1 = w2[(size_t)j * DHID_ + 2 * k2 + 1]; }
      unsigned p0 = pack_split(v0), p1 = pack_split(v1);
      apH[idx] = (p0 & 0xFFFFu) | (p1 << 16);
      apL[idx] = (p0 >> 16) | (p1 & 0xFFFF0000u);
    }
    flag_signal(&flags[F_PW]);
    return;
  }

  // ================================================================ prep_b (128 blocks × 32 rows, 2-phase)
  else if (bid < RB_GEMM) {
    const int q = bid - RB_PB;
    const int tid = threadIdx.x;
    // phase 1: emb part (k2<150) + zero pad (k2>=200) — no dependencies
    if (tid < KP_) {
      int k2 = tid;
      for (int rr = 0; rr < 32; ++rr) {
        int r = q * 32 + rr;
        int t2 = r >> 5, b2 = r & 31;
        if (k2 < 150) {
          const float* e2 = word_emb + (size_t)x[b2 * S_ + t2] * E_;
          unsigned p0 = pack_split(e2[2 * k2]), p1 = pack_split(e2[2 * k2 + 1]);
          bpH[(size_t)r * KP_ + k2] = (p0 & 0xFFFFu) | (p1 << 16);
          bpL[(size_t)r * KP_ + k2] = (p0 >> 16) | (p1 & 0xFFFF0000u);
        } else if (k2 >= 200) {
          bpH[(size_t)r * KP_ + k2] = 0u;
          bpL[(size_t)r * KP_ + k2] = 0u;
        }
      }
    }
    flag_signal(&flags[F_PBE]);
    // phase 2: pooled part (150<=k2<200) — needs conv3
    flag_wait(&flags[F_C3], NB_C3, 8);
    if (tid >= 150 && tid < 200) {
      int k2 = tid;
      for (int rr = 0; rr < 32; ++rr) {
        int r = q * 32 + rr;
        int b2 = r & 31;
        float v0 = pooled[b2 * C_ + 2 * k2 - 300];
        float v1 = pooled[b2 * C_ + 2 * k2 - 299];
        unsigned p0 = pack_split(v0), p1 = pack_split(v1);
        bpH[(size_t)r * KP_ + k2] = (p0 & 0xFFFFu) | (p1 << 16);
        bpL[(size_t)r * KP_ + k2] = (p0 >> 16) | (p1 & 0xFFFF0000u);
      }
    }
    flag_signal(&flags[F_PB]);
    return;
  }

  // ================================================================ input GEMM (512 blocks)
  else if (bid < RB_FC) {
    flag_wait(&flags[F_PW], NB_PW, 16);
    flag_wait(&flags[F_PBE], NB_PB, 16);   // Kt 0..8 (k2<144) needs only emb phase
    const int q = bid - RB_GEMM;
    // d fastest; backward direction consumes t descending -> give it rt descending
    const int d = q & 1;
    const int jt = (q >> 1) & 7;
    const int rtb = q >> 4;
    const int rt = d ? (31 - rtb) : rtb;
    const int j0 = jt * 128, r0 = rt * 128;
    const int tid = threadIdx.x;
    const int w = tid >> 6, l = tid & 63;
    const int lx = l & 15, lq = l >> 4;

    unsigned* aH = sm.gemm.aH;
    unsigned* aL = sm.gemm.aL;
    unsigned* bH = sm.gemm.bH;
    unsigned* bL = sm.gemm.bL;

    f32x4 acch[2][8], accl[2][8];
#pragma unroll
    for (int mt = 0; mt < 2; ++mt)
#pragma unroll
      for (int nt = 0; nt < 8; ++nt) {
        f32x4 z = {0.f, 0.f, 0.f, 0.f};
        acch[mt][nt] = z; accl[mt][nt] = z;
      }

    const int jr = tid >> 1, hh = tid & 1;
    const int q_st = jr >> 4, lane_lo = jr & 15;
    const unsigned* arH = apH + ((size_t)(d * G4_ + j0 + jr)) * KP_ + hh * 8;
    const unsigned* arL = apL + ((size_t)(d * G4_ + j0 + jr)) * KP_ + hh * 8;
    const unsigned* brH = bpH + ((size_t)(r0 + jr)) * KP_ + hh * 8;
    const unsigned* brL = bpL + ((size_t)(r0 + jr)) * KP_ + hh * 8;
    const int w0 = (q_st * 64 + lane_lo + 32 * hh) * 4;
    const int w1 = (q_st * 64 + lane_lo + 32 * hh + 16) * 4;

    for (int Kt = 0; Kt < 13; ++Kt) {
      if (Kt == 9) flag_wait(&flags[F_PB], NB_PB, 8);  // pooled region k2>=144 tile boundary
      uint4 a0 = *(const uint4*)(arH + Kt * 16);
      uint4 a1 = *(const uint4*)(arH + Kt * 16 + 4);
      uint4 c0v = *(const uint4*)(arL + Kt * 16);
      uint4 c1v = *(const uint4*)(arL + Kt * 16 + 4);
      uint4 e0 = *(const uint4*)(brH + Kt * 16);
      uint4 e1 = *(const uint4*)(brH + Kt * 16 + 4);
      uint4 f0 = *(const uint4*)(brL + Kt * 16);
      uint4 f1 = *(const uint4*)(brL + Kt * 16 + 4);
      *(uint4*)&aH[w0] = a0; *(uint4*)&aH[w1] = a1;
      *(uint4*)&aL[w0] = c0v; *(uint4*)&aL[w1] = c1v;
      *(uint4*)&bH[w0] = e0; *(uint4*)&bH[w1] = e1;
      *(uint4*)&bL[w0] = f0; *(uint4*)&bL[w1] = f1;
      __syncthreads();

      union u4h { uint4 u; half8 h; };
      u4h AH0, AH1, AL0, AL1;
      AH0.u = *(const uint4*)&aH[((2 * w + 0) * 64 + l) * 4];
      AH1.u = *(const uint4*)&aH[((2 * w + 1) * 64 + l) * 4];
      AL0.u = *(const uint4*)&aL[((2 * w + 0) * 64 + l) * 4];
      AL1.u = *(const uint4*)&aL[((2 * w + 1) * 64 + l) * 4];
#pragma unroll
      for (int nt = 0; nt < 8; ++nt) {
        u4h BHn, BLn;
        BHn.u = *(const uint4*)&bH[(nt * 64 + l) * 4];
        BLn.u = *(const uint4*)&bL[(nt * 64 + l) * 4];
        acch[0][nt] = __builtin_amdgcn_mfma_f32_16x16x32_f16(AH0.h, BHn.h, acch[0][nt], 0, 0, 0);
        accl[0][nt] = __builtin_amdgcn_mfma_f32_16x16x32_f16(AH0.h, BLn.h, accl[0][nt], 0, 0, 0);
        accl[0][nt] = __builtin_amdgcn_mfma_f32_16x16x32_f16(AL0.h, BHn.h, accl[0][nt], 0, 0, 0);
        acch[1][nt] = __builtin_amdgcn_mfma_f32_16x16x32_f16(AH1.h, BHn.h, acch[1][nt], 0, 0, 0);
        accl[1][nt] = __builtin_amdgcn_mfma_f32_16x16x32_f16(AH1.h, BLn.h, accl[1][nt], 0, 0, 0);
        accl[1][nt] = __builtin_amdgcn_mfma_f32_16x16x32_f16(AL1.h, BHn.h, accl[1][nt], 0, 0, 0);
      }
      __syncthreads();
    }

    const float* bias = d ? b_b : b_f;
    const float inv2048 = 1.0f / 2048.0f;
#pragma unroll
    for (int mt = 0; mt < 2; ++mt) {
#pragma unroll
      for (int nt = 0; nt < 8; ++nt) {
        int rr = r0 + nt * 16 + lx;
        int tt = rr >> 5, bb2 = rr & 31;
        unsigned* dst = (unsigned*)gi + ((size_t)(d * S_ + tt) * G4_) * B_ + bb2;
#pragma unroll
        for (int r4 = 0; r4 < 4; ++r4) {
          int j = j0 + (2 * w + mt) * 16 + lq * 4 + r4;
          float vv = acch[mt][nt][r4] + accl[mt][nt][r4] * inv2048 + bias[j];
          __hip_atomic_store(&dst[(size_t)j * B_], __builtin_bit_cast(unsigned, vv),
                             __ATOMIC_RELAXED, __HIP_MEMORY_SCOPE_AGENT);
        }
      }
    }
    // release-signal this (d, rt) tile: 8 jt-blocks per tile -> LSTM waits for ==8
    flag_signal(&flags[FG_BASE + d * 32 + rt]);
    return;
  }

  // ================================================================ FC -> emissions (128 blocks)
  else if (bid < RB_SMV) {
    const int s = bid - RB_FC;
    const int tid = threadIdx.x;
    float* wT = sm.fc.wT;
    float* psum = sm.fc.psum;
    for (int i = tid; i < L_ * 512; i += 256) {
      int l2 = i / 512, k = i % 512;
      wT[k * 18 + l2] = fc_w[i];
    }
    const float* hf = hbuf + (size_t)(s + 1) * (H_ * B_);
    const float* hbk = hbuf + (size_t)(S_ + 1 + (S_ - s)) * (H_ * B_);
    const unsigned* hfu = (const unsigned*)hf;
    const unsigned* hbku = (const unsigned*)hbk;
    // cheap proxy poll (1 broadcast word per direction) while the lstm runs
    for (;;) {
      unsigned a = __hip_atomic_load(&hfu[0], __ATOMIC_RELAXED, __HIP_MEMORY_SCOPE_AGENT);
      unsigned c = __hip_atomic_load(&hbku[0], __ATOMIC_RELAXED, __HIP_MEMORY_SCOPE_AGENT);
      if (a != SENTF_ && c != SENTF_) break;
      __builtin_amdgcn_s_sleep(32);
    }
    const int b2 = tid & 31, kq = tid >> 5;
    const unsigned* basep = (kq < 4) ? hfu : hbku;
    const int koff = (kq < 4) ? kq * 64 : kq * 64 - 256;
    unsigned hraw[64];
    for (;;) {
      bool pend = false;
#pragma unroll
      for (int i = 0; i < 64; ++i)
        hraw[i] = __hip_atomic_load(&basep[(size_t)(koff + i) * 32 + b2],
                                    __ATOMIC_RELAXED, __HIP_MEMORY_SCOPE_AGENT);
#pragma unroll
      for (int i = 0; i < 64; ++i) pend |= (hraw[i] == SENTF_);
      if (!pend) break;
      __builtin_amdgcn_s_sleep(8);
    }
    __syncthreads();
    float acc[L_];
#pragma unroll
    for (int l2 = 0; l2 < L_; ++l2) acc[l2] = 0.f;
#pragma unroll
    for (int i = 0; i < 64; ++i) {
      int k = kq * 64 + i;
      float hv = __builtin_bit_cast(float, hraw[i]);
      const float* wr = &wT[k * 18];
#pragma unroll
      for (int l2 = 0; l2 < L_; ++l2) acc[l2] = fmaf(hv, wr[l2], acc[l2]);
    }
#pragma unroll
    for (int l2 = 0; l2 < L_; ++l2) psum[tid * 18 + l2] = acc[l2];
    __syncthreads();
    for (int idx = tid; idx < B_ * L_; idx += 256) {
      int bb2 = idx & 31, l2 = idx >> 5;
      float sum = fc_b[l2];
      for (int q2 = 0; q2 < 8; ++q2) sum += psum[(q2 * 32 + bb2) * 18 + l2];
      __hip_atomic_store((unsigned*)&em[((size_t)bb2 * S_ + s) * L_ + l2],
                         __builtin_bit_cast(unsigned, sum),
                         __ATOMIC_RELAXED, __HIP_MEMORY_SCOPE_AGENT);
    }
    return;
  }

  // ================================================================ softmax + viterbi (32 blocks)
  else {
    const int bb = bid - RB_SMV;
    const int tid = threadIdx.x;
    float* e = sm.smv.e;
    float* tr = sm.smv.tr;
    auto sc = sm.smv.sc;
    int* hist = sm.smv.hist;
    int* tags = sm.smv.tags;

    int ei[9];
#pragma unroll
    for (int j = 0; j < 9; ++j) { int i = tid + j * 256; ei[j] = (i < S_ * L_) ? i : tid; }
    const unsigned* emu = (const unsigned*)em + (size_t)bb * S_ * L_;
    unsigned ev[9];
    for (;;) {
      bool pend = false;
#pragma unroll
      for (int j = 0; j < 9; ++j)
        ev[j] = __hip_atomic_load(&emu[ei[j]], __ATOMIC_RELAXED, __HIP_MEMORY_SCOPE_AGENT);
#pragma unroll
      for (int j = 0; j < 9; ++j) pend |= (ev[j] == SENTF_);
      if (!pend) break;
      __builtin_amdgcn_s_sleep(127);
    }
#pragma unroll
    for (int j = 0; j < 9; ++j) e[ei[j]] = __builtin_bit_cast(float, ev[j]);
    for (int i = tid; i < L_ * L_; i += 256) tr[i] = trans[i];
    __syncthreads();
    if (tid < L_) {
      int l2 = tid;
      float m = -INFINITY;
      for (int s2 = 0; s2 < S_; ++s2) m = fmaxf(m, e[s2 * L_ + l2]);
      float sum2 = 0.f;
      for (int s2 = 0; s2 < S_; ++s2) {
        float ex = expf(e[s2 * L_ + l2] - m);
        e[s2 * L_ + l2] = ex;
        sum2 += ex;
      }
      for (int s2 = 0; s2 < S_; ++s2) e[s2 * L_ + l2] = e[s2 * L_ + l2] / sum2;
    }
    __syncthreads();
    if (tid < L_) sc[0][tid] = start_t[tid] + e[tid];
    __syncthreads();
    int cbuf = 0;
    for (int t2 = 1; t2 < S_; ++t2) {
      if (tid < L_) {
        int j2 = tid;
        float evv = e[t2 * L_ + j2];
        float best = -INFINITY;
        int arg = 0;
        for (int i = 0; i < L_; ++i) {
          float v = (sc[cbuf][i] + tr[i * L_ + j2]) + evv;
          if (v > best) { best = v; arg = i; }  // strict >: first occurrence like np.argmax
        }
        int maskt = (x[bb * S_ + t2] != 0);
        sc[cbuf ^ 1][j2] = maskt ? best : sc[cbuf][j2];
        hist[(t2 - 1) * L_ + j2] = arg;
      }
      __syncthreads();
      cbuf ^= 1;
    }
    if (tid == 0) {
      float best = -INFINITY;
      int last = 0;
      for (int j2 = 0; j2 < L_; ++j2) {
        float v = sc[cbuf][j2] + end_t[j2];
        if (v > best) { best = v; last = j2; }
      }
      int cur = last;
      tags[S_ - 1] = cur;
      for (int p = S_ - 2; p >= 0; --p) {
        if (x[bb * S_ + p + 1] != 0) cur = hist[p * L_ + cur];
        tags[p] = cur;
      }
    }
    __syncthreads();
    for (int s2 = tid; s2 < S_; s2 += 256) out[bb * S_ + s2] = tags[s2];
    return;
  }
}

// ---------------------------------------------------------------- launch
extern "C" void kernel_launch(void* const* d_in, const int* in_sizes, int n_in,
                              void* d_out, int out_size, void* d_ws, size_t ws_size,
                              hipStream_t stream) {
  const int* x        = (const int*)d_in[0];
  const int* x_char   = (const int*)d_in[1];
  const float* word_emb = (const float*)d_in[2];
  const float* char_emb = (const float*)d_in[3];
  const float* conv1_w = (const float*)d_in[4];
  const float* conv1_b = (const float*)d_in[5];
  const float* conv2_w = (const float*)d_in[6];
  const float* conv2_b = (const float*)d_in[7];
  const float* conv3_w = (const float*)d_in[8];
  const float* conv3_b = (const float*)d_in[9];
  const float* w_ih_f = (const float*)d_in[10];
  const float* w_hh_f = (const float*)d_in[11];
  const float* b_f    = (const float*)d_in[12];
  const float* w_ih_b = (const float*)d_in[13];
  const float* w_hh_b = (const float*)d_in[14];
  const float* b_b    = (const float*)d_in[15];
  const float* h0     = (const float*)d_in[16];
  const float* c0     = (const float*)d_in[17];
  const float* fc_w   = (const float*)d_in[18];
  const float* fc_b   = (const float*)d_in[19];
  const float* start_t = (const float*)d_in[20];
  const float* trans  = (const float*)d_in[21];
  const float* end_t  = (const float*)d_in[22];
  int* out = (int*)d_out;

  char* ws = (char*)d_ws;
  auto alloc = [&](size_t bytes) -> char* {
    char* p = ws;
    ws += (bytes + 1023) & ~(size_t)1023;
    return p;
  };
  float* pooled  = (float*)alloc(sizeof(float) * B_ * C_);
  float* gi      = (float*)alloc(sizeof(float) * 2 * S_ * G4_ * B_);
  float* hbuf    = (float*)alloc(sizeof(float) * 2 * (S_ + 1) * H_ * B_);
  unsigned* hfrag = (unsigned*)alloc(sizeof(unsigned) * 2 * (S_ + 1) * SLAB_);
  unsigned* apH  = (unsigned*)alloc(sizeof(unsigned) * 2 * G4_ * KP_);
  unsigned* apL  = (unsigned*)alloc(sizeof(unsigned) * 2 * G4_ * KP_);
  unsigned* bpH  = (unsigned*)alloc(sizeof(unsigned) * 4096 * KP_);
  unsigned* bpL  = (unsigned*)alloc(sizeof(unsigned) * 4096 * KP_);
  float* out1    = (float*)alloc(sizeof(float) * B_ * C_ * 48);
  float* out2    = (float*)alloc(sizeof(float) * B_ * C_ * 45);
  float* em      = (float*)alloc(sizeof(float) * B_ * S_ * L_);
  int* flags     = (int*)alloc(sizeof(int) * 128);

  k_fill<<<2048, 256, 0, stream>>>(h0, hfrag, (unsigned*)hbuf, (unsigned*)em, flags);
  k_mega<<<NBLK_MEGA, 256, 0, stream>>>(
      x, x_char, word_emb, char_emb,
      conv1_w, conv1_b, conv2_w, conv2_b, conv3_w, conv3_b,
      w_ih_f, w_ih_b, w_hh_f, w_hh_b, b_f, b_b, c0, fc_w, fc_b,
      start_t, trans, end_t,
      pooled, gi, hbuf, hfrag, apH, apL, bpH, bpL, out1, out2, em, flags, out);
}